// Round 11
// baseline (1195.264 us; speedup 1.0000x reference)
//
#include <hip/hip_runtime.h>
#include <math.h>

// Shapes (fixed by setup_inputs)
#define BATCH 8
#define TSEQ 2048
#define CIN 3
#define WIN 5
#define LSEQ 2044          // T - WIN + 1
#define LH 2045            // LSEQ + 1 (cls token appended)
#define DIM 128
#define DEPTH 4
#define DIN 256            // d_inner
#define NH 4               // heads
#define PDIM 64            // headdim
#define NSTATE 64          // d_state
#define CONVD 384          // d_inner + 2*d_state
#define DPROJ 644          // 2*d_inner + 2*d_state + nheads
#define NJT 41             // j-tiles of 16 (41*16 = 656 >= 644)
#define QC 64              // chunk length
#define NCH 32             // number of chunks
#define LDS2 68            // padded LDS row stride (shorts, 64-col frag buffers)
#define LDSY 268           // padded stride (shorts): 134 dwords ≡ 6 mod 32 -> frag reads bank-free
#define LDSH 140           // padded stride (shorts): 70 dwords ≡ 6 mod 32 -> bank-free, 8B-aligned rows
#define FTR 32             // tokens per k_front block
#define OTOK 32            // tokens per k_out_fused block (512-thread block, 8 waves)

typedef __attribute__((ext_vector_type(8))) short bf16x8;
typedef __attribute__((ext_vector_type(4))) float f32x4;
union Frag8 { bf16x8 v; uint2 u[2]; };

__device__ __forceinline__ float sigmoidf_(float x){ return 1.f/(1.f+__expf(-x)); }
__device__ __forceinline__ float siluf_(float x){ return x*sigmoidf_(x); }
__device__ __forceinline__ unsigned short f2bf(float f){   // RNE fp32->bf16
  unsigned int u = __float_as_uint(f);
  return (unsigned short)((u + 0x7FFFu + ((u >> 16) & 1u)) >> 16);
}
__device__ __forceinline__ float bf2f(unsigned short u){
  return __uint_as_float(((unsigned int)u) << 16);
}
__device__ __forceinline__ unsigned int pack2(float a, float b){  // [lo addr]=a
  return (unsigned int)f2bf(a) | ((unsigned int)f2bf(b) << 16);
}
__device__ __forceinline__ unsigned int pack2lo(float a, float b){
  float ra = a - bf2f(f2bf(a)), rb = b - bf2f(f2bf(b));
  return (unsigned int)f2bf(ra) | ((unsigned int)f2bf(rb) << 16);
}
__device__ __forceinline__ bf16x8 ldfrag(const unsigned short* base, int off){
  Frag8 f;
  f.u[0] = *(const uint2*)(base + off);
  f.u[1] = *(const uint2*)(base + off + 4);
  return f.v;
}

// ---------------------------------------------------------------- merged weight-cast
// R29: blk 228 zeroes the per-(layer,group) combine counters (graph-replay safe:
// re-zeroed at the head of every launch, before any chunk_state runs).
__global__ void __launch_bounds__(256) k_cast_all(
    const float* __restrict__ w, const float* __restrict__ ow,
    unsigned short* __restrict__ wH, unsigned short* __restrict__ wL,
    unsigned short* __restrict__ oH, unsigned short* __restrict__ oL,
    unsigned int* __restrict__ cnt) {
  int blk = blockIdx.x;
  if (blk < 164) {                            // inw: [ly][jt][kb][lane], 164*256 = 41984
    int gid = blk*256 + threadIdx.x;
    int lane = gid & 63;
    int kb = (gid >> 6) & 3;
    int jt = (gid >> 8) % NJT;
    int ly = gid / (NJT*4*64);
    int m = lane & 15, q = lane >> 4;
    int j = jt*16 + m;
    int k = kb*32 + q*8;
    unsigned short hi[8], lo[8];
    if (j < DPROJ) {
      const float* src = w + ((size_t)ly*DPROJ + j)*DIM + k;
#pragma unroll
      for (int i = 0; i < 8; ++i) {
        float v = src[i];
        hi[i] = f2bf(v);
        lo[i] = f2bf(v - bf2f(hi[i]));
      }
    } else {
#pragma unroll
      for (int i = 0; i < 8; ++i) { hi[i] = 0; lo[i] = 0; }
    }
    size_t dst = (size_t)gid*8;
    *(uint4*)(wH + dst) = *(const uint4*)hi;
    *(uint4*)(wL + dst) = *(const uint4*)lo;
  } else if (blk < 228) {                     // ow: 64*256 = 16384
    int gid = (blk - 164)*256 + threadIdx.x;
    int lane = gid & 63;
    int kb = (gid >> 6) & 7;
    int jt = (gid >> 9) & 7;
    int ly = gid >> 12;
    int m = lane & 15, q = lane >> 4;
    int j = jt*16 + m;
    int k = kb*32 + q*8;
    const float* src = ow + ((size_t)ly*DIM + j)*DIN + k;
    unsigned short hi[8], lo[8];
#pragma unroll
    for (int i = 0; i < 8; ++i) {
      float v = src[i];
      hi[i] = f2bf(v);
      lo[i] = f2bf(v - bf2f(hi[i]));
    }
    size_t dst = (size_t)gid*8;
    *(uint4*)(oH + dst) = *(const uint4*)hi;
    *(uint4*)(oL + dst) = *(const uint4*)lo;
  } else {                                    // combine counters: DEPTH*32 = 128 uints
    int t = threadIdx.x;
    if (t < DEPTH*32) cnt[t] = 0u;
  }
}

// ---------------------------------------------------------------- front MLP + layer-0 in_proj
// R28: in_proj FUSED into k_front (bit-identical fragment math to the old
// k_inproj_mfma); 32-row h tile in a bf16 hi/lo LDS tile aliasing the dead
// xs/w1s/h1s region; cls row injected inline. (R10-verified: 494->474.)
__global__ void __launch_bounds__(512) k_front_proj(
    const float* __restrict__ x, const float* __restrict__ w1,
    const float* __restrict__ b1, const float* __restrict__ w2,
    const float* __restrict__ b2, const float* __restrict__ cls,
    const unsigned short* __restrict__ wH, const unsigned short* __restrict__ wL,
    const float* __restrict__ dtb, float* __restrict__ zx) {
  int t = threadIdx.x;
  int b = blockIdx.x >> 6;
  int c0 = (blockIdx.x & 63) * FTR;
  __shared__ __align__(16) float pool[108 + 2176 + 4096 + 8192];
  float* xs   = pool;
  float* w1s  = pool + 108;
  float* h1s  = pool + 108 + 2176;           // [32][128]
  float* part = pool + 108 + 2176 + 4096;    // [32][128][2]
  unsigned short* hsH = (unsigned short*)pool;
  unsigned short* hsL = hsH + 32*LDSH;       // aliases dead region by phase 3
  for (int i = t; i < (FTR+4)*CIN; i += 512) {
    int row = c0 + i/3, ch = i - (i/3)*3;
    xs[i] = (row < TSEQ) ? x[(size_t)b*TSEQ*CIN + (size_t)row*CIN + ch] : 0.f;
  }
  for (int i = t; i < DIM*15; i += 512) {
    int j = i/15, k = i - j*15;
    w1s[j*17+k] = w1[i];
  }
  __syncthreads();
  {
    int j = t & 127, rh = t >> 7;            // rh 0..3 -> 8 rows each
    float bias = b1[j];
    const float* wr = &w1s[j*17];
    for (int r = rh*8; r < rh*8+8; ++r) {
      float a = bias;
#pragma unroll
      for (int k = 0; k < 15; ++k) a += xs[r*3+k]*wr[k];
      h1s[r*128 + j] = 0.5f*a*(1.f + erff(a*0.70710678118654752f));  // exact gelu
    }
  }
  __syncthreads();
  {
    int j = t & 127, z = t >> 7;             // z 0..3
    int hf = z & 1, rh2 = z >> 1;            // k-half, row-half (16 rows)
    float4 wv[16];
    const float4* w2r = (const float4*)(w2 + (size_t)j*DIM + hf*64);
#pragma unroll
    for (int k4 = 0; k4 < 16; ++k4) wv[k4] = w2r[k4];
#pragma unroll 2
    for (int r = rh2*16; r < rh2*16+16; ++r) {
      const float4* hr = (const float4*)&h1s[r*128 + hf*64];
      float acc = 0.f;
#pragma unroll
      for (int k4 = 0; k4 < 16; ++k4) {
        float4 hv = hr[k4];
        acc += wv[k4].x*hv.x + wv[k4].y*hv.y + wv[k4].z*hv.z + wv[k4].w*hv.w;
      }
      part[(r*128 + j)*2 + hf] = acc;
    }
  }
  __syncthreads();
  {
    int c = t & 127, rh = t >> 7;            // 8 rows each
    float bias = b2[c];
    for (int r = rh*8; r < rh*8+8; ++r) {
      int l = c0 + r;
      float val;
      if (l < LSEQ)       val = part[(r*128 + c)*2] + part[(r*128 + c)*2 + 1] + bias;
      else if (l == LSEQ) val = cls[c];
      else                val = 0.f;
      unsigned short hi = f2bf(val);
      hsH[r*LDSH + c] = hi;
      hsL[r*LDSH + c] = f2bf(val - bf2f(hi));
    }
  }
  __syncthreads();
  int wave = t >> 6, lane = t & 63;
  int m = lane & 15, q = lane >> 4;
#pragma unroll 2
  for (int jt = wave; jt < NJT; jt += 8) {
    size_t woff = (((size_t)jt*4)*64 + lane)*8;
    bf16x8 bh[4], bl[4];
#pragma unroll
    for (int kb = 0; kb < 4; ++kb) {
      bh[kb] = *(const bf16x8*)(wH + woff + (size_t)kb*64*8);  // coalesced
      bl[kb] = *(const bf16x8*)(wL + woff + (size_t)kb*64*8);
    }
    f32x4 acc0 = {0.f, 0.f, 0.f, 0.f}, acc1 = {0.f, 0.f, 0.f, 0.f};
#pragma unroll
    for (int kb = 0; kb < 4; ++kb) {
      int o0 = m*LDSH + kb*32 + q*8;
      int o1 = (16 + m)*LDSH + kb*32 + q*8;  // 16*LDSH ≡ 0 mod 32 dwords
      bf16x8 a0h = ldfrag(hsH, o0), a0l = ldfrag(hsL, o0);
      bf16x8 a1h = ldfrag(hsH, o1), a1l = ldfrag(hsL, o1);
      acc0 = __builtin_amdgcn_mfma_f32_16x16x32_bf16(a0l, bh[kb], acc0, 0, 0, 0);
      acc0 = __builtin_amdgcn_mfma_f32_16x16x32_bf16(a0h, bl[kb], acc0, 0, 0, 0);
      acc0 = __builtin_amdgcn_mfma_f32_16x16x32_bf16(a0h, bh[kb], acc0, 0, 0, 0);
      acc1 = __builtin_amdgcn_mfma_f32_16x16x32_bf16(a1l, bh[kb], acc1, 0, 0, 0);
      acc1 = __builtin_amdgcn_mfma_f32_16x16x32_bf16(a1h, bl[kb], acc1, 0, 0, 0);
      acc1 = __builtin_amdgcn_mfma_f32_16x16x32_bf16(a1h, bh[kb], acc1, 0, 0, 0);
    }
    int jj = jt*16 + m;
    if (jj < DPROJ) {
      bool isdt = (jj >= 640);
      float bias = isdt ? dtb[jj - 640] : 0.f;
#pragma unroll
      for (int r = 0; r < 4; ++r) {
        int tok = c0 + q*4 + r;
        if (tok < LH) {
          float vv = acc0[r];
          if (isdt) { vv += bias; vv = (vv > 20.f) ? vv : log1pf(__expf(vv)); }
          zx[((size_t)b*LH + tok)*DPROJ + jj] = vv;
        }
        int tok1 = c0 + 16 + q*4 + r;
        if (tok1 < LH) {
          float vv = acc1[r];
          if (isdt) { vv += bias; vv = (vv > 20.f) ? vv : log1pf(__expf(vv)); }
          zx[((size_t)b*LH + tok1)*DPROJ + jj] = vv;
        }
      }
    }
  }
}

// ---------------------------------------------------------------- causal dwconv + silu
__global__ void k_conv(const float* __restrict__ zx, const float* __restrict__ cw,
                       const float* __restrict__ cb, float* __restrict__ xbc) {
  size_t idx = (size_t)blockIdx.x*blockDim.x + threadIdx.x;
  const size_t total = (size_t)BATCH*LH*(CONVD/4);
  if (idx >= total) return;
  int c4 = (int)(idx % (CONVD/4)) * 4;
  size_t bl = idx / (CONVD/4);
  int l = (int)(bl % LH); int b = (int)(bl / LH);
  float4 w0 = *(const float4*)(cw + (c4+0)*4);
  float4 w1 = *(const float4*)(cw + (c4+1)*4);
  float4 w2 = *(const float4*)(cw + (c4+2)*4);
  float4 w3 = *(const float4*)(cw + (c4+3)*4);
  float4 a = *(const float4*)(cb + c4);
#pragma unroll
  for (int k = 0; k < 4; ++k) {
    int tin = l - 3 + k;
    if (tin >= 0) {
      float4 v = *(const float4*)(zx + ((size_t)b*LH + tin)*DPROJ + DIN + c4);
      a.x += v.x * ((const float*)&w0)[k];
      a.y += v.y * ((const float*)&w1)[k];
      a.z += v.z * ((const float*)&w2)[k];
      a.w += v.w * ((const float*)&w3)[k];
    }
  }
  float4 o;
  o.x = siluf_(a.x); o.y = siluf_(a.y); o.z = siluf_(a.z); o.w = siluf_(a.w);
  *(float4*)(xbc + ((size_t)b*LH + l)*CONVD + c4) = o;
}

// ---------------------------------------------------------------- chunked SSD, phase A
// R23/R24: register-prefetched staging; dt load hoisted.
// R29: inter-chunk combine FUSED as a last-block-of-group epilogue (replaces
// k_combine dispatch). Each block: G writes -> threadfence -> atomicAdd on the
// group counter; the 32nd block runs the group scan (4 esp-slices interleaved
// in one 4-deep pipeline; per-element FP order identical to old k_combine).
__global__ void __launch_bounds__(256, 4) k_chunk_state(
    const float* __restrict__ zx, const float* __restrict__ xbc,
    const float* __restrict__ A_log, float* __restrict__ G, float* __restrict__ dec,
    float* __restrict__ Hin, unsigned int* __restrict__ cnt) {
  int blk = blockIdx.x;
  int c = blk & (NCH-1), hd = (blk >> 5) & 3, b = blk >> 7;
  int t0 = c*QC;
  int tid = threadIdx.x;
  int wv = tid >> 6, lane = tid & 63;
  int m = lane & 15, q = lane >> 4;
  float A = -__expf(A_log[hd]);
  __shared__ __align__(16) unsigned short BcH[QC*LDS2], BcL[QC*LDS2]; // [n][s]
  __shared__ __align__(16) unsigned short XtH[QC*LDS2], XtL[QC*LDS2]; // [p][s]
  __shared__ float coef[QC];
  __shared__ unsigned int lastflag;
  float dtv = 0.f;
  if (tid < 64) {
    int tg = t0 + tid;
    dtv = (tg < LH) ? zx[((size_t)b*LH + tg)*DPROJ + 640 + hd] : 0.f;
  }
  float pb[16], px[16];
#pragma unroll
  for (int it = 0; it < 8; ++it) {
    int i = tid + it*256;
    int n = i & 63, s2 = (i >> 6)*2;
    int tg0 = t0 + s2, tg1 = tg0 + 1;
    float b0 = 0.f, b1 = 0.f, x0 = 0.f, x1 = 0.f;
    if (tg0 < LH) {
      size_t row = ((size_t)b*LH + tg0)*CONVD;
      b0 = xbc[row + DIN + n];
      x0 = xbc[row + hd*PDIM + n];
    }
    if (tg1 < LH) {
      size_t row = ((size_t)b*LH + tg1)*CONVD;
      b1 = xbc[row + DIN + n];
      x1 = xbc[row + hd*PDIM + n];
    }
    pb[it*2] = b0; pb[it*2+1] = b1; px[it*2] = x0; px[it*2+1] = x1;
  }
  if (tid < 64) {
    float s = dtv;
#pragma unroll
    for (int off = 1; off < 64; off <<= 1) {
      float u = __shfl_up(s, off);
      if (tid >= off) s += u;
    }
    float cq = __shfl(s, 63);
    coef[tid] = __expf(A*(cq - s)) * dtv;
    if (tid == 63) dec[blk] = __expf(A * s);
  }
  __syncthreads();
#pragma unroll
  for (int it = 0; it < 8; ++it) {
    int i = tid + it*256;
    int n = i & 63, s2 = (i >> 6)*2;
    float c0_ = coef[s2], c1_ = coef[s2+1];
    float b0 = pb[it*2]*c0_, b1 = pb[it*2+1]*c1_;
    float x0 = px[it*2],     x1 = px[it*2+1];
    int o = n*LDS2 + s2;
    *(unsigned int*)(BcH + o) = pack2(b0, b1);
    *(unsigned int*)(BcL + o) = pack2lo(b0, b1);
    *(unsigned int*)(XtH + o) = pack2(x0, x1);
    *(unsigned int*)(XtL + o) = pack2lo(x0, x1);
  }
  __syncthreads();
  bf16x8 ah[2], al[2];
#pragma unroll
  for (int kc = 0; kc < 2; ++kc) {
    int off = (wv*16 + m)*LDS2 + kc*32 + q*8;
    ah[kc] = ldfrag(BcH, off);
    al[kc] = ldfrag(BcL, off);
  }
#pragma unroll
  for (int nt = 0; nt < 4; ++nt) {
    f32x4 acc = {0.f,0.f,0.f,0.f};
#pragma unroll
    for (int kc = 0; kc < 2; ++kc) {
      int off = (nt*16 + m)*LDS2 + kc*32 + q*8;
      bf16x8 xh = ldfrag(XtH, off), xl = ldfrag(XtL, off);
      acc = __builtin_amdgcn_mfma_f32_16x16x32_bf16(al[kc], xh, acc, 0, 0, 0);
      acc = __builtin_amdgcn_mfma_f32_16x16x32_bf16(ah[kc], xl, acc, 0, 0, 0);
      acc = __builtin_amdgcn_mfma_f32_16x16x32_bf16(ah[kc], xh, acc, 0, 0, 0);
    }
    int p = nt*16 + m;
#pragma unroll
    for (int r = 0; r < 4; ++r) {
      int n = wv*16 + q*4 + r;
      G[(size_t)blk*4096 + n*64 + p] = acc[r];
    }
  }
  // ---- last-block-of-group combine epilogue (R29)
  __threadfence();                    // release: G + dec globally visible
  __syncthreads();
  if (tid == 0) lastflag = (atomicAdd(&cnt[blk >> 5], 1u) == (unsigned)(NCH - 1));
  __syncthreads();
  if (lastflag) {
    __threadfence();                  // acquire: see siblings' G + dec
    int bh = blk >> 5;
    size_t gbase = (size_t)bh*(size_t)NCH*4096;
    int e = tid*4;
    float4 gq0[4], gq1[4], gq2[4], gq3[4]; float dq[4];
#pragma unroll
    for (int k = 0; k < 4; ++k) {
      size_t kb = gbase + (size_t)k*4096 + e;
      gq0[k] = *(const float4*)(G + kb);
      gq1[k] = *(const float4*)(G + kb + 1024);
      gq2[k] = *(const float4*)(G + kb + 2048);
      gq3[k] = *(const float4*)(G + kb + 3072);
      dq[k] = dec[bh*NCH + k];
    }
    float4 H0 = make_float4(0.f,0.f,0.f,0.f), H1 = H0, H2 = H0, H3 = H0;
#pragma unroll 4
    for (int cc = 0; cc < NCH; ++cc) {
      int slot = cc & 3;
      float d = dq[slot];
      float4 g0 = gq0[slot], g1 = gq1[slot], g2 = gq2[slot], g3 = gq3[slot];
      if (cc + 4 < NCH) {
        size_t kb = gbase + (size_t)(cc+4)*4096 + e;
        gq0[slot] = *(const float4*)(G + kb);
        gq1[slot] = *(const float4*)(G + kb + 1024);
        gq2[slot] = *(const float4*)(G + kb + 2048);
        gq3[slot] = *(const float4*)(G + kb + 3072);
        dq[slot] = dec[bh*NCH + cc + 4];
      }
      size_t ob = gbase + (size_t)cc*4096 + e;
      *(float4*)(Hin + ob)        = H0;
      *(float4*)(Hin + ob + 1024) = H1;
      *(float4*)(Hin + ob + 2048) = H2;
      *(float4*)(Hin + ob + 3072) = H3;
      H0.x = H0.x*d + g0.x; H0.y = H0.y*d + g0.y; H0.z = H0.z*d + g0.z; H0.w = H0.w*d + g0.w;
      H1.x = H1.x*d + g1.x; H1.y = H1.y*d + g1.y; H1.z = H1.z*d + g1.z; H1.w = H1.w*d + g1.w;
      H2.x = H2.x*d + g2.x; H2.y = H2.y*d + g2.y; H2.z = H2.z*d + g2.z; H2.w = H2.w*d + g2.w;
      H3.x = H3.x*d + g3.x; H3.y = H3.y*d + g3.y; H3.z = H3.z*d + g3.z; H3.w = H3.w*d + g3.w;
    }
  }
}

// ---------------------------------------------------------------- phase C: chunk output
// R21 LDS multiplex (2 buffer pairs, 4 blocks/CU); R24 register prefetches.
__global__ void __launch_bounds__(256, 4) k_chunk_out(
    const float* __restrict__ zx, const float* __restrict__ xbc,
    const float* __restrict__ A_log, const float* __restrict__ Hin,
    float* __restrict__ y) {
  int blk = blockIdx.x;
  int c = blk & (NCH-1), hd = (blk >> 5) & 3, b = blk >> 7;
  int t0 = c*QC;
  int tid = threadIdx.x;
  int wv = tid >> 6, lane = tid & 63;
  int m = lane & 15, q = lane >> 4;
  float A = -__expf(A_log[hd]);
  __shared__ __align__(16) unsigned short P0H[QC*LDS2], P0L[QC*LDS2]; // C, then mask
  __shared__ __align__(16) unsigned short P1H[QC*LDS2], P1L[QC*LDS2]; // B, HinT, Xt
  __shared__ float cum[QC], dts[QC], pref[QC];
  float dtv = 0.f;
  if (tid < 64) {
    int tg = t0 + tid;
    dtv = (tg < LH) ? zx[((size_t)b*LH + tg)*DPROJ + 640 + hd] : 0.f;
  }
  float pbv[16], pcv[16];
#pragma unroll
  for (int it = 0; it < 8; ++it) {
    int i = tid + it*256;
    int s = i >> 5, j2 = (i & 31)*2;
    int tg = t0 + s;
    float b0 = 0.f, b1 = 0.f, c0_ = 0.f, c1_ = 0.f;
    if (tg < LH) {
      size_t row = ((size_t)b*LH + tg)*CONVD;
      float2 bv = *(const float2*)(xbc + row + DIN + j2);
      float2 cv = *(const float2*)(xbc + row + DIN + NSTATE + j2);
      b0 = bv.x; b1 = bv.y; c0_ = cv.x; c1_ = cv.y;
    }
    pbv[it*2] = b0; pbv[it*2+1] = b1; pcv[it*2] = c0_; pcv[it*2+1] = c1_;
  }
  size_t hbase = (size_t)blk*4096;
  float hv[16];
#pragma unroll
  for (int it = 0; it < 8; ++it) {
    int i = tid + it*256;
    int p = i & 63, n2 = (i >> 6)*2;
    hv[it*2]   = Hin[hbase + (size_t)n2*64 + p];
    hv[it*2+1] = Hin[hbase + (size_t)(n2+1)*64 + p];
  }
  if (tid < 64) {
    float s = dtv;
#pragma unroll
    for (int off = 1; off < 64; off <<= 1) {
      float u = __shfl_up(s, off);
      if (tid >= off) s += u;
    }
    dts[tid] = dtv; cum[tid] = s; pref[tid] = __expf(A*s);
  }
#pragma unroll
  for (int it = 0; it < 8; ++it) {
    int i = tid + it*256;
    int s = i >> 5, j2 = (i & 31)*2;
    int o = s*LDS2 + j2;
    *(unsigned int*)(P1H + o) = pack2(pbv[it*2], pbv[it*2+1]);
    *(unsigned int*)(P1L + o) = pack2lo(pbv[it*2], pbv[it*2+1]);
    *(unsigned int*)(P0H + o) = pack2(pcv[it*2], pcv[it*2+1]);
    *(unsigned int*)(P0L + o) = pack2lo(pcv[it*2], pcv[it*2+1]);
  }
  __syncthreads();                                    // A
  bf16x8 ch[2], cl[2];
#pragma unroll
  for (int kc = 0; kc < 2; ++kc) {
    int off = (wv*16 + m)*LDS2 + kc*32 + q*8;
    ch[kc] = ldfrag(P0H, off);
    cl[kc] = ldfrag(P0L, off);
  }
  f32x4 sacc[4];
#pragma unroll
  for (int nt = 0; nt < 4; ++nt) {
    f32x4 a1 = {0.f,0.f,0.f,0.f};
#pragma unroll
    for (int kc = 0; kc < 2; ++kc) {
      int off = (nt*16 + m)*LDS2 + kc*32 + q*8;
      bf16x8 bh = ldfrag(P1H, off), bl = ldfrag(P1L, off);
      a1 = __builtin_amdgcn_mfma_f32_16x16x32_bf16(cl[kc], bh, a1, 0, 0, 0);
      a1 = __builtin_amdgcn_mfma_f32_16x16x32_bf16(ch[kc], bl, a1, 0, 0, 0);
      a1 = __builtin_amdgcn_mfma_f32_16x16x32_bf16(ch[kc], bh, a1, 0, 0, 0);
    }
    sacc[nt] = a1;
  }
  __syncthreads();                                    // B: C,B dead
  float xv[16];
#pragma unroll
  for (int it = 0; it < 8; ++it) {
    int i = tid + it*256;
    int p = i & 63, s2 = (i >> 6)*2;
    int tg = t0 + s2;
    xv[it*2]   = (tg < LH)   ? xbc[((size_t)b*LH + tg)*CONVD + hd*PDIM + p]   : 0.f;
    xv[it*2+1] = (tg+1 < LH) ? xbc[((size_t)b*LH + tg+1)*CONVD + hd*PDIM + p] : 0.f;
  }
#pragma unroll
  for (int nt = 0; nt < 4; ++nt) {
    int s = nt*16 + m;
#pragma unroll
    for (int r = 0; r < 4; ++r) {
      int t = wv*16 + q*4 + r;
      float mv = 0.f;
      if (s <= t) mv = sacc[nt][r] * __expf(A*(cum[t] - cum[s])) * dts[s];
      unsigned short hi = f2bf(mv);
      P0H[t*LDS2 + s] = hi;
      P0L[t*LDS2 + s] = f2bf(mv - bf2f(hi));
    }
  }
#pragma unroll
  for (int it = 0; it < 8; ++it) {
    int i = tid + it*256;
    int p = i & 63, n2 = (i >> 6)*2;
    int o = p*LDS2 + n2;
    *(unsigned int*)(P1H + o) = pack2(hv[it*2], hv[it*2+1]);
    *(unsigned int*)(P1L + o) = pack2lo(hv[it*2], hv[it*2+1]);
  }
  __syncthreads();                                    // C
  f32x4 y2a[4];
#pragma unroll
  for (int nt = 0; nt < 4; ++nt) {
    f32x4 a2 = {0.f,0.f,0.f,0.f};
#pragma unroll
    for (int kc = 0; kc < 2; ++kc) {
      int off = (nt*16 + m)*LDS2 + kc*32 + q*8;
      bf16x8 th = ldfrag(P1H, off), tl = ldfrag(P1L, off);
      a2 = __builtin_amdgcn_mfma_f32_16x16x32_bf16(cl[kc], th, a2, 0, 0, 0);
      a2 = __builtin_amdgcn_mfma_f32_16x16x32_bf16(ch[kc], tl, a2, 0, 0, 0);
      a2 = __builtin_amdgcn_mfma_f32_16x16x32_bf16(ch[kc], th, a2, 0, 0, 0);
    }
    y2a[nt] = a2;
  }
  bf16x8 mh[2], ml[2];
#pragma unroll
  for (int kc = 0; kc < 2; ++kc) {
    int off = (wv*16 + m)*LDS2 + kc*32 + q*8;
    mh[kc] = ldfrag(P0H, off);
    ml[kc] = ldfrag(P0L, off);
  }
  __syncthreads();                                    // D: Hin dead
#pragma unroll
  for (int it = 0; it < 8; ++it) {
    int i = tid + it*256;
    int p = i & 63, s2 = (i >> 6)*2;
    int o = p*LDS2 + s2;
    *(unsigned int*)(P1H + o) = pack2(xv[it*2], xv[it*2+1]);
    *(unsigned int*)(P1L + o) = pack2lo(xv[it*2], xv[it*2+1]);
  }
  __syncthreads();                                    // E
#pragma unroll
  for (int nt = 0; nt < 4; ++nt) {
    f32x4 a1 = {0.f,0.f,0.f,0.f};
#pragma unroll
    for (int kc = 0; kc < 2; ++kc) {
      int off = (nt*16 + m)*LDS2 + kc*32 + q*8;
      bf16x8 th = ldfrag(P1H, off), tl = ldfrag(P1L, off);
      a1 = __builtin_amdgcn_mfma_f32_16x16x32_bf16(ml[kc], th, a1, 0, 0, 0);
      a1 = __builtin_amdgcn_mfma_f32_16x16x32_bf16(mh[kc], tl, a1, 0, 0, 0);
      a1 = __builtin_amdgcn_mfma_f32_16x16x32_bf16(mh[kc], th, a1, 0, 0, 0);
    }
    int p = nt*16 + m;
#pragma unroll
    for (int r = 0; r < 4; ++r) {
      int t = wv*16 + q*4 + r, tg = t0 + t;
      if (tg < LH)
        y[((size_t)b*LH + tg)*DIN + hd*PDIM + p] = a1[r] + pref[t]*y2a[nt][r];
    }
  }
}

// ---------------------------------------------------------------- gate+rmsnorm+out_proj
// FUSED with next layer's in_proj. R22 512-thread OTOK=32; R23 weight prefetch.
__global__ void __launch_bounds__(512, 4) k_out_fused(
    const float* __restrict__ y, const float* __restrict__ xbc,
    float* __restrict__ zx, const float* __restrict__ Dh,
    const float* __restrict__ nw, const unsigned short* __restrict__ oH,
    const unsigned short* __restrict__ oL,
    const unsigned short* __restrict__ wH, const unsigned short* __restrict__ wL,
    const float* __restrict__ dtb, float* __restrict__ hout, int doProj) {
  int b = blockIdx.x >> 6;
  int l0 = (blockIdx.x & 63) * OTOK;
  int t = threadIdx.x;
  __shared__ __align__(16) unsigned short yH[OTOK*LDSY], yL[OTOK*LDSY];
  __shared__ __align__(16) unsigned short hsH[OTOK*LDSH], hsL[OTOK*LDSH];
  __shared__ float red[OTOK][4];
  __shared__ float rs[OTOK];
  int wave = t >> 6, lane = t & 63;
  bf16x8 pwh[4], pwl[4];
#pragma unroll
  for (int kb = 0; kb < 4; ++kb) {
    size_t woff = (((size_t)wave*8 + kb)*64 + lane)*8;
    pwh[kb] = *(const bf16x8*)(oH + woff);
    pwl[kb] = *(const bf16x8*)(oL + woff);
  }
  int c = t & 255;
  int rh = t >> 8;           // row-half: 0 -> rows 0..15, 1 -> rows 16..31
  int r0 = rh*16;
  int hd = c >> 6;
  float dcoef = Dh[hd];
  float nwc = nw[c];
  float v[16];
#pragma unroll
  for (int r = 0; r < 16; ++r) {
    int l = l0 + r0 + r;
    float val = 0.f;
    if (l < LH) {
      size_t row = (size_t)b*LH + l;
      float ys = y[row*DIN + c];
      float xh = xbc[row*CONVD + c];
      float z  = zx[row*DPROJ + c];
      val = (ys + dcoef*xh) * siluf_(z);
    }
    v[r] = val;
  }
  int qw = wave & 3;         // channel-quarter within the row-half
#pragma unroll
  for (int r = 0; r < 16; ++r) {
    float sq = v[r]*v[r];
    for (int off = 32; off > 0; off >>= 1) sq += __shfl_down(sq, off);
    if (lane == 0) red[r0 + r][qw] = sq;
  }
  __syncthreads();
  if (t < OTOK) {
    float sm = red[t][0]+red[t][1]+red[t][2]+red[t][3];
    rs[t] = rsqrtf(sm/(float)DIN + 1e-5f);
  }
  __syncthreads();
#pragma unroll
  for (int r = 0; r < 16; ++r) {
    float val = v[r] * rs[r0 + r] * nwc;
    unsigned short hi = f2bf(val);
    yH[(r0 + r)*LDSY + c] = hi;
    yL[(r0 + r)*LDSY + c] = f2bf(val - bf2f(hi));
  }
  __syncthreads();
  int m = lane & 15, q = lane >> 4;
  {
    int jt = wave;                          // 8 waves <-> 8 j-tiles
    f32x4 acc0 = {0.f,0.f,0.f,0.f}, acc1 = {0.f,0.f,0.f,0.f};
#pragma unroll
    for (int kb = 0; kb < 8; ++kb) {
      bf16x8 bh, bl;
      if (kb < 4) { bh = pwh[kb]; bl = pwl[kb]; }
      else {
        size_t woff = (((size_t)jt*8 + kb)*64 + lane)*8;   // coalesced
        bh = *(const bf16x8*)(oH + woff);
        bl = *(const bf16x8*)(oL + woff);
      }
      int o0 = m*LDSY + kb*32 + q*8;
      int o1 = (16 + m)*LDSY + kb*32 + q*8;  // 16*LDSY ≡ 0 mod 32 dwords: same bank pattern
      bf16x8 a0h = ldfrag(yH, o0), a0l = ldfrag(yL, o0);
      bf16x8 a1h = ldfrag(yH, o1), a1l = ldfrag(yL, o1);
      acc0 = __builtin_amdgcn_mfma_f32_16x16x32_bf16(a0l, bh, acc0, 0, 0, 0);
      acc0 = __builtin_amdgcn_mfma_f32_16x16x32_bf16(a0h, bl, acc0, 0, 0, 0);
      acc0 = __builtin_amdgcn_mfma_f32_16x16x32_bf16(a0h, bh, acc0, 0, 0, 0);
      acc1 = __builtin_amdgcn_mfma_f32_16x16x32_bf16(a1l, bh, acc1, 0, 0, 0);
      acc1 = __builtin_amdgcn_mfma_f32_16x16x32_bf16(a1h, bl, acc1, 0, 0, 0);
      acc1 = __builtin_amdgcn_mfma_f32_16x16x32_bf16(a1h, bh, acc1, 0, 0, 0);
    }
    int j = jt*16 + m;                      // D col = lane&15
#pragma unroll
    for (int r = 0; r < 4; ++r) {
      int rr = q*4 + r;                     // frag 0 rows
      float val = acc0[r];
      unsigned short hi = f2bf(val);
      hsH[rr*LDSH + j] = hi;
      hsL[rr*LDSH + j] = f2bf(val - bf2f(hi));
      int l = l0 + rr;
      if (!doProj && l < LH) hout[((size_t)b*LH + l)*DIM + j] = val;
      int rr1 = 16 + q*4 + r;               // frag 1 rows
      float val1 = acc1[r];
      unsigned short hi1 = f2bf(val1);
      hsH[rr1*LDSH + j] = hi1;
      hsL[rr1*LDSH + j] = f2bf(val1 - bf2f(hi1));
      int l1 = l0 + rr1;
      if (!doProj && l1 < LH) hout[((size_t)b*LH + l1)*DIM + j] = val1;
    }
  }
  if (!doProj) return;
  __syncthreads();
  // ---- in_proj of next layer from the LDS h tile (32 rows, 8 waves)
#pragma unroll 2
  for (int jt = wave; jt < NJT; jt += 8) {
    size_t woff = (((size_t)jt*4)*64 + lane)*8;
    bf16x8 bh[4], bl[4];
#pragma unroll
    for (int kb = 0; kb < 4; ++kb) {
      bh[kb] = *(const bf16x8*)(wH + woff + (size_t)kb*64*8);  // coalesced
      bl[kb] = *(const bf16x8*)(wL + woff + (size_t)kb*64*8);
    }
    f32x4 acc0 = {0.f, 0.f, 0.f, 0.f}, acc1 = {0.f, 0.f, 0.f, 0.f};
#pragma unroll
    for (int kb = 0; kb < 4; ++kb) {
      int o0 = m*LDSH + kb*32 + q*8;
      int o1 = (16 + m)*LDSH + kb*32 + q*8;  // 16*LDSH ≡ 0 mod 32 dwords
      bf16x8 a0h = ldfrag(hsH, o0), a0l = ldfrag(hsL, o0);
      bf16x8 a1h = ldfrag(hsH, o1), a1l = ldfrag(hsL, o1);
      acc0 = __builtin_amdgcn_mfma_f32_16x16x32_bf16(a0l, bh[kb], acc0, 0, 0, 0);
      acc0 = __builtin_amdgcn_mfma_f32_16x16x32_bf16(a0h, bl[kb], acc0, 0, 0, 0);
      acc0 = __builtin_amdgcn_mfma_f32_16x16x32_bf16(a0h, bh[kb], acc0, 0, 0, 0);
      acc1 = __builtin_amdgcn_mfma_f32_16x16x32_bf16(a1l, bh[kb], acc1, 0, 0, 0);
      acc1 = __builtin_amdgcn_mfma_f32_16x16x32_bf16(a1h, bl[kb], acc1, 0, 0, 0);
      acc1 = __builtin_amdgcn_mfma_f32_16x16x32_bf16(a1h, bh[kb], acc1, 0, 0, 0);
    }
    int jj = jt*16 + m;
    if (jj < DPROJ) {
      bool isdt = (jj >= 640);
      float bias = isdt ? dtb[jj - 640] : 0.f;
#pragma unroll
      for (int r = 0; r < 4; ++r) {
        int tok = l0 + q*4 + r;
        if (tok < LH) {
          float vv = acc0[r];
          if (isdt) { vv += bias; vv = (vv > 20.f) ? vv : log1pf(__expf(vv)); }
          zx[((size_t)b*LH + tok)*DPROJ + jj] = vv;
        }
        int tok1 = l0 + 16 + q*4 + r;
        if (tok1 < LH) {
          float vv = acc1[r];
          if (isdt) { vv += bias; vv = (vv > 20.f) ? vv : log1pf(__expf(vv)); }
          zx[((size_t)b*LH + tok1)*DPROJ + jj] = vv;
        }
      }
    }
  }
}

// ---------------------------------------------------------------- final LN + head
__global__ void k_head(const float* __restrict__ h, const float* __restrict__ lnw,
                       const float* __restrict__ lnb, const float* __restrict__ hw,
                       const float* __restrict__ hb, float* __restrict__ out) {
  int b = blockIdx.x; int t = threadIdx.x;
  __shared__ float red[2];
  int wave = t >> 6, lane = t & 63;
  float v = h[((size_t)b*LH + LSEQ)*DIM + t];
  float s = v;
  for (int off = 32; off > 0; off >>= 1) s += __shfl_down(s, off);
  if (lane == 0) red[wave] = s;
  __syncthreads();
  float mean = (red[0]+red[1]) / (float)DIM;
  __syncthreads();
  float d = v - mean; float sq = d*d;
  for (int off = 32; off > 0; off >>= 1) sq += __shfl_down(sq, off);
  if (lane == 0) red[wave] = sq;
  __syncthreads();
  float var = (red[0]+red[1]) / (float)DIM;
  float cn = d*rsqrtf(var + 1e-5f)*lnw[t] + lnb[t];
  float dot = cn*hw[t];
  __syncthreads();
  for (int off = 32; off > 0; off >>= 1) dot += __shfl_down(dot, off);
  if (lane == 0) red[wave] = dot;
  __syncthreads();
  if (t == 0) out[b] = red[0]+red[1] + hb[0];
}

extern "C" void kernel_launch(void* const* d_in, const int* in_sizes, int n_in,
                              void* d_out, int out_size, void* d_ws, size_t ws_size,
                              hipStream_t stream) {
  const float* x     = (const float*)d_in[0];
  const float* w1    = (const float*)d_in[1];
  const float* b1    = (const float*)d_in[2];
  const float* w2    = (const float*)d_in[3];
  const float* b2    = (const float*)d_in[4];
  const float* cls   = (const float*)d_in[5];
  const float* inw   = (const float*)d_in[6];   // (4, 644, 128)
  const float* cw    = (const float*)d_in[7];   // (4, 384, 4)
  const float* cb    = (const float*)d_in[8];   // (4, 384)
  const float* dtb   = (const float*)d_in[9];   // (4, 4)
  const float* Alog  = (const float*)d_in[10];  // (4, 4)
  const float* Dh    = (const float*)d_in[11];  // (4, 4)
  const float* nw    = (const float*)d_in[12];  // (4, 256)
  const float* ow    = (const float*)d_in[13];  // (4, 128, 256)
  const float* lnw   = (const float*)d_in[14];
  const float* lnb   = (const float*)d_in[15];
  const float* hw    = (const float*)d_in[16];
  const float* hb    = (const float*)d_in[17];

  float* ws   = (float*)d_ws;
  float* zx   = ws;                                   // 10,535,840
  float* xbc  = zx + (size_t)BATCH*LH*DPROJ;          // 6,282,240
  float* ybuf = xbc + (size_t)BATCH*LH*CONVD;         // 4,194,304 (G aliases ybuf)
  float* G    = ybuf;
  float* Hin  = ybuf + 4194304;                       // 4,194,304
  float* dec  = Hin  + 4194304;                       // 1,024
  unsigned short* wH = (unsigned short*)(dec + 1024);      // 4*41*4*64*8 u16
  unsigned short* wL = wH + (size_t)DEPTH*NJT*4*64*8;      // same
  unsigned short* oH = wL + (size_t)DEPTH*NJT*4*64*8;      // 4*8*8*64*8 u16
  unsigned short* oL = oH + (size_t)DEPTH*8*8*64*8;        // same
  unsigned int*   cnt = (unsigned int*)(oL + (size_t)DEPTH*8*8*64*8); // 128 uints

  float* hout = (float*)d_out + 8;   // final h written directly into output

  k_cast_all<<<229, 256, 0, stream>>>(inw, ow, wH, wL, oH, oL, cnt);

  k_front_proj<<<BATCH*64, 512, 0, stream>>>(x, w1, b1, w2, b2, cls,
                                             wH, wL, dtb, zx);

  for (int i = 0; i < DEPTH; ++i) {
    int doProj = (i < DEPTH-1) ? 1 : 0;
    int nxt = doProj ? (i+1) : 0;
    k_conv<<<(int)(((long)BATCH*LH*(CONVD/4) + 255)/256), 256, 0, stream>>>(
        zx, cw + (size_t)i*CONVD*4, cb + (size_t)i*CONVD, xbc);
    k_chunk_state<<<BATCH*NH*NCH, 256, 0, stream>>>(
        zx, xbc, Alog + i*NH, G, dec, Hin, cnt + i*32);
    k_chunk_out<<<BATCH*NH*NCH, 256, 0, stream>>>(zx, xbc, Alog + i*NH, Hin, ybuf);
    k_out_fused<<<BATCH*64, 512, 0, stream>>>(
        ybuf, xbc, zx, Dh + i*NH, nw + (size_t)i*DIN,
        oH + (size_t)i*8*8*64*8, oL + (size_t)i*8*8*64*8,
        wH + (size_t)nxt*NJT*4*64*8, wL + (size_t)nxt*NJT*4*64*8,
        dtb + nxt*NH, hout, doProj);
  }

  k_head<<<BATCH, 128, 0, stream>>>(hout, lnw, lnb, hw, hb, (float*)d_out);
}

// Round 12
// 469.861 us; speedup vs baseline: 2.5439x; 2.5439x over previous
//
#include <hip/hip_runtime.h>
#include <math.h>

// Shapes (fixed by setup_inputs)
#define BATCH 8
#define TSEQ 2048
#define CIN 3
#define WIN 5
#define LSEQ 2044          // T - WIN + 1
#define LH 2045            // LSEQ + 1 (cls token appended)
#define DIM 128
#define DEPTH 4
#define DIN 256            // d_inner
#define NH 4               // heads
#define PDIM 64            // headdim
#define NSTATE 64          // d_state
#define CONVD 384          // d_inner + 2*d_state
#define DPROJ 644          // 2*d_inner + 2*d_state + nheads
#define NJT 41             // j-tiles of 16 (41*16 = 656 >= 644)
#define QC 64              // chunk length
#define NCH 32             // number of chunks
#define LDS2 68            // padded LDS row stride (shorts, 64-col frag buffers)
#define LDSY 268           // padded stride (shorts): 134 dwords ≡ 6 mod 32 -> frag reads bank-free
#define LDSH 140           // padded stride (shorts): 70 dwords ≡ 6 mod 32 -> bank-free, 8B-aligned rows
#define FTR 32             // tokens per k_front block
#define OTOK 32            // tokens per k_out_fused block (512-thread block, 8 waves)

typedef __attribute__((ext_vector_type(8))) short bf16x8;
typedef __attribute__((ext_vector_type(4))) float f32x4;
union Frag8 { bf16x8 v; uint2 u[2]; };

__device__ __forceinline__ float sigmoidf_(float x){ return 1.f/(1.f+__expf(-x)); }
__device__ __forceinline__ float siluf_(float x){ return x*sigmoidf_(x); }
__device__ __forceinline__ unsigned short f2bf(float f){   // RNE fp32->bf16
  unsigned int u = __float_as_uint(f);
  return (unsigned short)((u + 0x7FFFu + ((u >> 16) & 1u)) >> 16);
}
__device__ __forceinline__ float bf2f(unsigned short u){
  return __uint_as_float(((unsigned int)u) << 16);
}
__device__ __forceinline__ unsigned int pack2(float a, float b){  // [lo addr]=a
  return (unsigned int)f2bf(a) | ((unsigned int)f2bf(b) << 16);
}
__device__ __forceinline__ unsigned int pack2lo(float a, float b){
  float ra = a - bf2f(f2bf(a)), rb = b - bf2f(f2bf(b));
  return (unsigned int)f2bf(ra) | ((unsigned int)f2bf(rb) << 16);
}
__device__ __forceinline__ bf16x8 ldfrag(const unsigned short* base, int off){
  Frag8 f;
  f.u[0] = *(const uint2*)(base + off);
  f.u[1] = *(const uint2*)(base + off + 4);
  return f.v;
}

// ---------------------------------------------------------------- merged weight-cast
__global__ void __launch_bounds__(256) k_cast_all(
    const float* __restrict__ w, const float* __restrict__ ow,
    unsigned short* __restrict__ wH, unsigned short* __restrict__ wL,
    unsigned short* __restrict__ oH, unsigned short* __restrict__ oL) {
  int blk = blockIdx.x;
  if (blk < 164) {                            // inw: [ly][jt][kb][lane], 164*256 = 41984
    int gid = blk*256 + threadIdx.x;
    int lane = gid & 63;
    int kb = (gid >> 6) & 3;
    int jt = (gid >> 8) % NJT;
    int ly = gid / (NJT*4*64);
    int m = lane & 15, q = lane >> 4;
    int j = jt*16 + m;
    int k = kb*32 + q*8;
    unsigned short hi[8], lo[8];
    if (j < DPROJ) {
      const float* src = w + ((size_t)ly*DPROJ + j)*DIM + k;
#pragma unroll
      for (int i = 0; i < 8; ++i) {
        float v = src[i];
        hi[i] = f2bf(v);
        lo[i] = f2bf(v - bf2f(hi[i]));
      }
    } else {
#pragma unroll
      for (int i = 0; i < 8; ++i) { hi[i] = 0; lo[i] = 0; }
    }
    size_t dst = (size_t)gid*8;
    *(uint4*)(wH + dst) = *(const uint4*)hi;
    *(uint4*)(wL + dst) = *(const uint4*)lo;
  } else {                                    // ow: 64*256 = 16384
    int gid = (blk - 164)*256 + threadIdx.x;
    int lane = gid & 63;
    int kb = (gid >> 6) & 7;
    int jt = (gid >> 9) & 7;
    int ly = gid >> 12;
    int m = lane & 15, q = lane >> 4;
    int j = jt*16 + m;
    int k = kb*32 + q*8;
    const float* src = ow + ((size_t)ly*DIM + j)*DIN + k;
    unsigned short hi[8], lo[8];
#pragma unroll
    for (int i = 0; i < 8; ++i) {
      float v = src[i];
      hi[i] = f2bf(v);
      lo[i] = f2bf(v - bf2f(hi[i]));
    }
    size_t dst = (size_t)gid*8;
    *(uint4*)(oH + dst) = *(const uint4*)hi;
    *(uint4*)(oL + dst) = *(const uint4*)lo;
  }
}

// ---------------------------------------------------------------- front MLP + layer-0 in_proj
// R28 (R10-verified 494->474): in_proj fused; h tile in aliased bf16 LDS; cls inline.
__global__ void __launch_bounds__(512) k_front_proj(
    const float* __restrict__ x, const float* __restrict__ w1,
    const float* __restrict__ b1, const float* __restrict__ w2,
    const float* __restrict__ b2, const float* __restrict__ cls,
    const unsigned short* __restrict__ wH, const unsigned short* __restrict__ wL,
    const float* __restrict__ dtb, float* __restrict__ zx) {
  int t = threadIdx.x;
  int b = blockIdx.x >> 6;
  int c0 = (blockIdx.x & 63) * FTR;
  __shared__ __align__(16) float pool[108 + 2176 + 4096 + 8192];
  float* xs   = pool;
  float* w1s  = pool + 108;
  float* h1s  = pool + 108 + 2176;           // [32][128]
  float* part = pool + 108 + 2176 + 4096;    // [32][128][2]
  unsigned short* hsH = (unsigned short*)pool;
  unsigned short* hsL = hsH + 32*LDSH;       // aliases dead region by phase 3
  for (int i = t; i < (FTR+4)*CIN; i += 512) {
    int row = c0 + i/3, ch = i - (i/3)*3;
    xs[i] = (row < TSEQ) ? x[(size_t)b*TSEQ*CIN + (size_t)row*CIN + ch] : 0.f;
  }
  for (int i = t; i < DIM*15; i += 512) {
    int j = i/15, k = i - j*15;
    w1s[j*17+k] = w1[i];
  }
  __syncthreads();
  {
    int j = t & 127, rh = t >> 7;            // rh 0..3 -> 8 rows each
    float bias = b1[j];
    const float* wr = &w1s[j*17];
    for (int r = rh*8; r < rh*8+8; ++r) {
      float a = bias;
#pragma unroll
      for (int k = 0; k < 15; ++k) a += xs[r*3+k]*wr[k];
      h1s[r*128 + j] = 0.5f*a*(1.f + erff(a*0.70710678118654752f));  // exact gelu
    }
  }
  __syncthreads();
  {
    int j = t & 127, z = t >> 7;             // z 0..3
    int hf = z & 1, rh2 = z >> 1;            // k-half, row-half (16 rows)
    float4 wv[16];
    const float4* w2r = (const float4*)(w2 + (size_t)j*DIM + hf*64);
#pragma unroll
    for (int k4 = 0; k4 < 16; ++k4) wv[k4] = w2r[k4];
#pragma unroll 2
    for (int r = rh2*16; r < rh2*16+16; ++r) {
      const float4* hr = (const float4*)&h1s[r*128 + hf*64];
      float acc = 0.f;
#pragma unroll
      for (int k4 = 0; k4 < 16; ++k4) {
        float4 hv = hr[k4];
        acc += wv[k4].x*hv.x + wv[k4].y*hv.y + wv[k4].z*hv.z + wv[k4].w*hv.w;
      }
      part[(r*128 + j)*2 + hf] = acc;
    }
  }
  __syncthreads();
  {
    int c = t & 127, rh = t >> 7;            // 8 rows each
    float bias = b2[c];
    for (int r = rh*8; r < rh*8+8; ++r) {
      int l = c0 + r;
      float val;
      if (l < LSEQ)       val = part[(r*128 + c)*2] + part[(r*128 + c)*2 + 1] + bias;
      else if (l == LSEQ) val = cls[c];
      else                val = 0.f;
      unsigned short hi = f2bf(val);
      hsH[r*LDSH + c] = hi;
      hsL[r*LDSH + c] = f2bf(val - bf2f(hi));
    }
  }
  __syncthreads();
  int wave = t >> 6, lane = t & 63;
  int m = lane & 15, q = lane >> 4;
#pragma unroll 2
  for (int jt = wave; jt < NJT; jt += 8) {
    size_t woff = (((size_t)jt*4)*64 + lane)*8;
    bf16x8 bh[4], bl[4];
#pragma unroll
    for (int kb = 0; kb < 4; ++kb) {
      bh[kb] = *(const bf16x8*)(wH + woff + (size_t)kb*64*8);  // coalesced
      bl[kb] = *(const bf16x8*)(wL + woff + (size_t)kb*64*8);
    }
    f32x4 acc0 = {0.f, 0.f, 0.f, 0.f}, acc1 = {0.f, 0.f, 0.f, 0.f};
#pragma unroll
    for (int kb = 0; kb < 4; ++kb) {
      int o0 = m*LDSH + kb*32 + q*8;
      int o1 = (16 + m)*LDSH + kb*32 + q*8;  // 16*LDSH ≡ 0 mod 32 dwords
      bf16x8 a0h = ldfrag(hsH, o0), a0l = ldfrag(hsL, o0);
      bf16x8 a1h = ldfrag(hsH, o1), a1l = ldfrag(hsL, o1);
      acc0 = __builtin_amdgcn_mfma_f32_16x16x32_bf16(a0l, bh[kb], acc0, 0, 0, 0);
      acc0 = __builtin_amdgcn_mfma_f32_16x16x32_bf16(a0h, bl[kb], acc0, 0, 0, 0);
      acc0 = __builtin_amdgcn_mfma_f32_16x16x32_bf16(a0h, bh[kb], acc0, 0, 0, 0);
      acc1 = __builtin_amdgcn_mfma_f32_16x16x32_bf16(a1l, bh[kb], acc1, 0, 0, 0);
      acc1 = __builtin_amdgcn_mfma_f32_16x16x32_bf16(a1h, bl[kb], acc1, 0, 0, 0);
      acc1 = __builtin_amdgcn_mfma_f32_16x16x32_bf16(a1h, bh[kb], acc1, 0, 0, 0);
    }
    int jj = jt*16 + m;
    if (jj < DPROJ) {
      bool isdt = (jj >= 640);
      float bias = isdt ? dtb[jj - 640] : 0.f;
#pragma unroll
      for (int r = 0; r < 4; ++r) {
        int tok = c0 + q*4 + r;
        if (tok < LH) {
          float vv = acc0[r];
          if (isdt) { vv += bias; vv = (vv > 20.f) ? vv : log1pf(__expf(vv)); }
          zx[((size_t)b*LH + tok)*DPROJ + jj] = vv;
        }
        int tok1 = c0 + 16 + q*4 + r;
        if (tok1 < LH) {
          float vv = acc1[r];
          if (isdt) { vv += bias; vv = (vv > 20.f) ? vv : log1pf(__expf(vv)); }
          zx[((size_t)b*LH + tok1)*DPROJ + jj] = vv;
        }
      }
    }
  }
}

// ---------------------------------------------------------------- causal dwconv + silu
__global__ void k_conv(const float* __restrict__ zx, const float* __restrict__ cw,
                       const float* __restrict__ cb, float* __restrict__ xbc) {
  size_t idx = (size_t)blockIdx.x*blockDim.x + threadIdx.x;
  const size_t total = (size_t)BATCH*LH*(CONVD/4);
  if (idx >= total) return;
  int c4 = (int)(idx % (CONVD/4)) * 4;
  size_t bl = idx / (CONVD/4);
  int l = (int)(bl % LH); int b = (int)(bl / LH);
  float4 w0 = *(const float4*)(cw + (c4+0)*4);
  float4 w1 = *(const float4*)(cw + (c4+1)*4);
  float4 w2 = *(const float4*)(cw + (c4+2)*4);
  float4 w3 = *(const float4*)(cw + (c4+3)*4);
  float4 a = *(const float4*)(cb + c4);
#pragma unroll
  for (int k = 0; k < 4; ++k) {
    int tin = l - 3 + k;
    if (tin >= 0) {
      float4 v = *(const float4*)(zx + ((size_t)b*LH + tin)*DPROJ + DIN + c4);
      a.x += v.x * ((const float*)&w0)[k];
      a.y += v.y * ((const float*)&w1)[k];
      a.z += v.z * ((const float*)&w2)[k];
      a.w += v.w * ((const float*)&w3)[k];
    }
  }
  float4 o;
  o.x = siluf_(a.x); o.y = siluf_(a.y); o.z = siluf_(a.z); o.w = siluf_(a.w);
  *(float4*)(xbc + ((size_t)b*LH + l)*CONVD + c4) = o;
}

// ---------------------------------------------------------------- chunked SSD, phase A
// R30: 512 threads (8 waves = row-group wr x tile-half wh) — same LDS, same
// grid, waves/CU doubles for this latency-bound kernel. Staging loops stride
// 512 (identical element->pair mapping -> bit-identical LDS contents); each
// wave computes 2 of 4 nt tiles with its row-group's fragments (same MFMA
// calls/order per output element as the 256-thread version).
__global__ void __launch_bounds__(512, 8) k_chunk_state(
    const float* __restrict__ zx, const float* __restrict__ xbc,
    const float* __restrict__ A_log, float* __restrict__ G, float* __restrict__ dec) {
  int blk = blockIdx.x;
  int c = blk & (NCH-1), hd = (blk >> 5) & 3, b = blk >> 7;
  int t0 = c*QC;
  int tid = threadIdx.x;
  int wave = tid >> 6, lane = tid & 63;
  int wr = wave & 3, wh = wave >> 2;
  int m = lane & 15, q = lane >> 4;
  float A = -__expf(A_log[hd]);
  __shared__ __align__(16) unsigned short BcH[QC*LDS2], BcL[QC*LDS2]; // [n][s]
  __shared__ __align__(16) unsigned short XtH[QC*LDS2], XtL[QC*LDS2]; // [p][s]
  __shared__ float coef[QC];
  float dtv = 0.f;
  if (tid < 64) {
    int tg = t0 + tid;
    dtv = (tg < LH) ? zx[((size_t)b*LH + tg)*DPROJ + 640 + hd] : 0.f;
  }
  float pb[8], px[8];
#pragma unroll
  for (int it = 0; it < 4; ++it) {
    int i = tid + it*512;
    int n = i & 63, s2 = (i >> 6)*2;
    int tg0 = t0 + s2, tg1 = tg0 + 1;
    float b0 = 0.f, b1 = 0.f, x0 = 0.f, x1 = 0.f;
    if (tg0 < LH) {
      size_t row = ((size_t)b*LH + tg0)*CONVD;
      b0 = xbc[row + DIN + n];
      x0 = xbc[row + hd*PDIM + n];
    }
    if (tg1 < LH) {
      size_t row = ((size_t)b*LH + tg1)*CONVD;
      b1 = xbc[row + DIN + n];
      x1 = xbc[row + hd*PDIM + n];
    }
    pb[it*2] = b0; pb[it*2+1] = b1; px[it*2] = x0; px[it*2+1] = x1;
  }
  if (tid < 64) {
    float s = dtv;
#pragma unroll
    for (int off = 1; off < 64; off <<= 1) {
      float u = __shfl_up(s, off);
      if (tid >= off) s += u;
    }
    float cq = __shfl(s, 63);
    coef[tid] = __expf(A*(cq - s)) * dtv;
    if (tid == 63) dec[blk] = __expf(A * s);
  }
  __syncthreads();
#pragma unroll
  for (int it = 0; it < 4; ++it) {
    int i = tid + it*512;
    int n = i & 63, s2 = (i >> 6)*2;
    float c0_ = coef[s2], c1_ = coef[s2+1];
    float b0 = pb[it*2]*c0_, b1 = pb[it*2+1]*c1_;
    float x0 = px[it*2],     x1 = px[it*2+1];
    int o = n*LDS2 + s2;
    *(unsigned int*)(BcH + o) = pack2(b0, b1);
    *(unsigned int*)(BcL + o) = pack2lo(b0, b1);
    *(unsigned int*)(XtH + o) = pack2(x0, x1);
    *(unsigned int*)(XtL + o) = pack2lo(x0, x1);
  }
  __syncthreads();
  bf16x8 ah[2], al[2];
#pragma unroll
  for (int kc = 0; kc < 2; ++kc) {
    int off = (wr*16 + m)*LDS2 + kc*32 + q*8;
    ah[kc] = ldfrag(BcH, off);
    al[kc] = ldfrag(BcL, off);
  }
#pragma unroll
  for (int nth = 0; nth < 2; ++nth) {
    int nt = wh*2 + nth;
    f32x4 acc = {0.f,0.f,0.f,0.f};
#pragma unroll
    for (int kc = 0; kc < 2; ++kc) {
      int off = (nt*16 + m)*LDS2 + kc*32 + q*8;
      bf16x8 xh = ldfrag(XtH, off), xl = ldfrag(XtL, off);
      acc = __builtin_amdgcn_mfma_f32_16x16x32_bf16(al[kc], xh, acc, 0, 0, 0);
      acc = __builtin_amdgcn_mfma_f32_16x16x32_bf16(ah[kc], xl, acc, 0, 0, 0);
      acc = __builtin_amdgcn_mfma_f32_16x16x32_bf16(ah[kc], xh, acc, 0, 0, 0);
    }
    int p = nt*16 + m;
#pragma unroll
    for (int r = 0; r < 4; ++r) {
      int n = wr*16 + q*4 + r;
      G[(size_t)blk*4096 + n*64 + p] = acc[r];
    }
  }
}

// ---------------------------------------------------------------- phase B: inter-chunk
// R24: 4-deep rotating load pipeline. (R11's fused last-block version regressed
// 2.5x: a single block is capped at per-CU bandwidth — keep the 128-block kernel.)
__global__ void __launch_bounds__(256) k_combine(
    const float* __restrict__ G, const float* __restrict__ dec, float* __restrict__ Hin) {
  int bh = blockIdx.x >> 2, esp = blockIdx.x & 3;
  int e = esp*1024 + threadIdx.x*4;
  size_t base0 = (size_t)bh*NCH*4096 + e;
  float4 gq[4]; float dq[4];
#pragma unroll
  for (int k = 0; k < 4; ++k) {
    gq[k] = *(const float4*)(G + base0 + (size_t)k*4096);
    dq[k] = dec[bh*NCH + k];
  }
  float4 H = make_float4(0.f,0.f,0.f,0.f);
#pragma unroll 4
  for (int c = 0; c < NCH; ++c) {
    int slot = c & 3;
    float4 g = gq[slot]; float d = dq[slot];
    if (c + 4 < NCH) {
      gq[slot] = *(const float4*)(G + base0 + (size_t)(c+4)*4096);
      dq[slot] = dec[bh*NCH + c + 4];
    }
    *(float4*)(Hin + base0 + (size_t)c*4096) = H;   // carry-in for chunk c
    H.x = H.x*d + g.x; H.y = H.y*d + g.y; H.z = H.z*d + g.z; H.w = H.w*d + g.w;
  }
}

// ---------------------------------------------------------------- phase C: chunk output
// R30: 512 threads (8 waves = wr x wh), same LDS (35.8 KB, 4 blocks/CU) ->
// up to 32 waves/CU. Each wave: A-fragments from row-group wr, computes
// nt in {2wh, 2wh+1}. Mask/output coverage: (t-group wr) x (s/p-groups 2wh,
// 2wh+1) -> all 16 combos across 8 waves. FP math per element unchanged.
__global__ void __launch_bounds__(512, 8) k_chunk_out(
    const float* __restrict__ zx, const float* __restrict__ xbc,
    const float* __restrict__ A_log, const float* __restrict__ Hin,
    float* __restrict__ y) {
  int blk = blockIdx.x;
  int c = blk & (NCH-1), hd = (blk >> 5) & 3, b = blk >> 7;
  int t0 = c*QC;
  int tid = threadIdx.x;
  int wave = tid >> 6, lane = tid & 63;
  int wr = wave & 3, wh = wave >> 2;
  int m = lane & 15, q = lane >> 4;
  float A = -__expf(A_log[hd]);
  __shared__ __align__(16) unsigned short P0H[QC*LDS2], P0L[QC*LDS2]; // C, then mask
  __shared__ __align__(16) unsigned short P1H[QC*LDS2], P1L[QC*LDS2]; // B, HinT, Xt
  __shared__ float cum[QC], dts[QC], pref[QC];
  float dtv = 0.f;
  if (tid < 64) {
    int tg = t0 + tid;
    dtv = (tg < LH) ? zx[((size_t)b*LH + tg)*DPROJ + 640 + hd] : 0.f;
  }
  float pbv[8], pcv[8];
#pragma unroll
  for (int it = 0; it < 4; ++it) {
    int i = tid + it*512;
    int s = i >> 5, j2 = (i & 31)*2;
    int tg = t0 + s;
    float b0 = 0.f, b1 = 0.f, c0_ = 0.f, c1_ = 0.f;
    if (tg < LH) {
      size_t row = ((size_t)b*LH + tg)*CONVD;
      float2 bv = *(const float2*)(xbc + row + DIN + j2);
      float2 cv = *(const float2*)(xbc + row + DIN + NSTATE + j2);
      b0 = bv.x; b1 = bv.y; c0_ = cv.x; c1_ = cv.y;
    }
    pbv[it*2] = b0; pbv[it*2+1] = b1; pcv[it*2] = c0_; pcv[it*2+1] = c1_;
  }
  size_t hbase = (size_t)blk*4096;
  float hv[8];
#pragma unroll
  for (int it = 0; it < 4; ++it) {
    int i = tid + it*512;
    int p = i & 63, n2 = (i >> 6)*2;
    hv[it*2]   = Hin[hbase + (size_t)n2*64 + p];
    hv[it*2+1] = Hin[hbase + (size_t)(n2+1)*64 + p];
  }
  if (tid < 64) {
    float s = dtv;
#pragma unroll
    for (int off = 1; off < 64; off <<= 1) {
      float u = __shfl_up(s, off);
      if (tid >= off) s += u;
    }
    dts[tid] = dtv; cum[tid] = s; pref[tid] = __expf(A*s);
  }
#pragma unroll
  for (int it = 0; it < 4; ++it) {
    int i = tid + it*512;
    int s = i >> 5, j2 = (i & 31)*2;
    int o = s*LDS2 + j2;
    *(unsigned int*)(P1H + o) = pack2(pbv[it*2], pbv[it*2+1]);
    *(unsigned int*)(P1L + o) = pack2lo(pbv[it*2], pbv[it*2+1]);
    *(unsigned int*)(P0H + o) = pack2(pcv[it*2], pcv[it*2+1]);
    *(unsigned int*)(P0L + o) = pack2lo(pcv[it*2], pcv[it*2+1]);
  }
  __syncthreads();                                    // A
  bf16x8 ch[2], cl[2];
#pragma unroll
  for (int kc = 0; kc < 2; ++kc) {
    int off = (wr*16 + m)*LDS2 + kc*32 + q*8;
    ch[kc] = ldfrag(P0H, off);
    cl[kc] = ldfrag(P0L, off);
  }
  f32x4 sacc[2];
#pragma unroll
  for (int nth = 0; nth < 2; ++nth) {
    int nt = wh*2 + nth;
    f32x4 a1 = {0.f,0.f,0.f,0.f};
#pragma unroll
    for (int kc = 0; kc < 2; ++kc) {
      int off = (nt*16 + m)*LDS2 + kc*32 + q*8;
      bf16x8 bh = ldfrag(P1H, off), bl = ldfrag(P1L, off);
      a1 = __builtin_amdgcn_mfma_f32_16x16x32_bf16(cl[kc], bh, a1, 0, 0, 0);
      a1 = __builtin_amdgcn_mfma_f32_16x16x32_bf16(ch[kc], bl, a1, 0, 0, 0);
      a1 = __builtin_amdgcn_mfma_f32_16x16x32_bf16(ch[kc], bh, a1, 0, 0, 0);
    }
    sacc[nth] = a1;
  }
  __syncthreads();                                    // B: C,B dead
  float xv[8];
#pragma unroll
  for (int it = 0; it < 4; ++it) {
    int i = tid + it*512;
    int p = i & 63, s2 = (i >> 6)*2;
    int tg = t0 + s2;
    xv[it*2]   = (tg < LH)   ? xbc[((size_t)b*LH + tg)*CONVD + hd*PDIM + p]   : 0.f;
    xv[it*2+1] = (tg+1 < LH) ? xbc[((size_t)b*LH + tg+1)*CONVD + hd*PDIM + p] : 0.f;
  }
#pragma unroll
  for (int nth = 0; nth < 2; ++nth) {
    int nt = wh*2 + nth;
    int s = nt*16 + m;
#pragma unroll
    for (int r = 0; r < 4; ++r) {
      int t = wr*16 + q*4 + r;
      float mv = 0.f;
      if (s <= t) mv = sacc[nth][r] * __expf(A*(cum[t] - cum[s])) * dts[s];
      unsigned short hi = f2bf(mv);
      P0H[t*LDS2 + s] = hi;
      P0L[t*LDS2 + s] = f2bf(mv - bf2f(hi));
    }
  }
#pragma unroll
  for (int it = 0; it < 4; ++it) {
    int i = tid + it*512;
    int p = i & 63, n2 = (i >> 6)*2;
    int o = p*LDS2 + n2;
    *(unsigned int*)(P1H + o) = pack2(hv[it*2], hv[it*2+1]);
    *(unsigned int*)(P1L + o) = pack2lo(hv[it*2], hv[it*2+1]);
  }
  __syncthreads();                                    // C
  f32x4 y2a[2];
#pragma unroll
  for (int nth = 0; nth < 2; ++nth) {
    int nt = wh*2 + nth;
    f32x4 a2 = {0.f,0.f,0.f,0.f};
#pragma unroll
    for (int kc = 0; kc < 2; ++kc) {
      int off = (nt*16 + m)*LDS2 + kc*32 + q*8;
      bf16x8 th = ldfrag(P1H, off), tl = ldfrag(P1L, off);
      a2 = __builtin_amdgcn_mfma_f32_16x16x32_bf16(cl[kc], th, a2, 0, 0, 0);
      a2 = __builtin_amdgcn_mfma_f32_16x16x32_bf16(ch[kc], tl, a2, 0, 0, 0);
      a2 = __builtin_amdgcn_mfma_f32_16x16x32_bf16(ch[kc], th, a2, 0, 0, 0);
    }
    y2a[nth] = a2;
  }
  bf16x8 mh[2], ml[2];
#pragma unroll
  for (int kc = 0; kc < 2; ++kc) {
    int off = (wr*16 + m)*LDS2 + kc*32 + q*8;
    mh[kc] = ldfrag(P0H, off);
    ml[kc] = ldfrag(P0L, off);
  }
  __syncthreads();                                    // D: Hin dead
#pragma unroll
  for (int it = 0; it < 4; ++it) {
    int i = tid + it*512;
    int p = i & 63, s2 = (i >> 6)*2;
    int o = p*LDS2 + s2;
    *(unsigned int*)(P1H + o) = pack2(xv[it*2], xv[it*2+1]);
    *(unsigned int*)(P1L + o) = pack2lo(xv[it*2], xv[it*2+1]);
  }
  __syncthreads();                                    // E
#pragma unroll
  for (int nth = 0; nth < 2; ++nth) {
    int nt = wh*2 + nth;
    f32x4 a1 = {0.f,0.f,0.f,0.f};
#pragma unroll
    for (int kc = 0; kc < 2; ++kc) {
      int off = (nt*16 + m)*LDS2 + kc*32 + q*8;
      bf16x8 th = ldfrag(P1H, off), tl = ldfrag(P1L, off);
      a1 = __builtin_amdgcn_mfma_f32_16x16x32_bf16(ml[kc], th, a1, 0, 0, 0);
      a1 = __builtin_amdgcn_mfma_f32_16x16x32_bf16(mh[kc], tl, a1, 0, 0, 0);
      a1 = __builtin_amdgcn_mfma_f32_16x16x32_bf16(mh[kc], th, a1, 0, 0, 0);
    }
    int p = nt*16 + m;
#pragma unroll
    for (int r = 0; r < 4; ++r) {
      int t = wr*16 + q*4 + r, tg = t0 + t;
      if (tg < LH)
        y[((size_t)b*LH + tg)*DIN + hd*PDIM + p] = a1[r] + pref[t]*y2a[nth][r];
    }
  }
}

// ---------------------------------------------------------------- gate+rmsnorm+out_proj
// FUSED with next layer's in_proj. R22 512-thread OTOK=32; R23 weight prefetch.
__global__ void __launch_bounds__(512, 4) k_out_fused(
    const float* __restrict__ y, const float* __restrict__ xbc,
    float* __restrict__ zx, const float* __restrict__ Dh,
    const float* __restrict__ nw, const unsigned short* __restrict__ oH,
    const unsigned short* __restrict__ oL,
    const unsigned short* __restrict__ wH, const unsigned short* __restrict__ wL,
    const float* __restrict__ dtb, float* __restrict__ hout, int doProj) {
  int b = blockIdx.x >> 6;
  int l0 = (blockIdx.x & 63) * OTOK;
  int t = threadIdx.x;
  __shared__ __align__(16) unsigned short yH[OTOK*LDSY], yL[OTOK*LDSY];
  __shared__ __align__(16) unsigned short hsH[OTOK*LDSH], hsL[OTOK*LDSH];
  __shared__ float red[OTOK][4];
  __shared__ float rs[OTOK];
  int wave = t >> 6, lane = t & 63;
  bf16x8 pwh[4], pwl[4];
#pragma unroll
  for (int kb = 0; kb < 4; ++kb) {
    size_t woff = (((size_t)wave*8 + kb)*64 + lane)*8;
    pwh[kb] = *(const bf16x8*)(oH + woff);
    pwl[kb] = *(const bf16x8*)(oL + woff);
  }
  int c = t & 255;
  int rh = t >> 8;           // row-half: 0 -> rows 0..15, 1 -> rows 16..31
  int r0 = rh*16;
  int hd = c >> 6;
  float dcoef = Dh[hd];
  float nwc = nw[c];
  float v[16];
#pragma unroll
  for (int r = 0; r < 16; ++r) {
    int l = l0 + r0 + r;
    float val = 0.f;
    if (l < LH) {
      size_t row = (size_t)b*LH + l;
      float ys = y[row*DIN + c];
      float xh = xbc[row*CONVD + c];
      float z  = zx[row*DPROJ + c];
      val = (ys + dcoef*xh) * siluf_(z);
    }
    v[r] = val;
  }
  int qw = wave & 3;         // channel-quarter within the row-half
#pragma unroll
  for (int r = 0; r < 16; ++r) {
    float sq = v[r]*v[r];
    for (int off = 32; off > 0; off >>= 1) sq += __shfl_down(sq, off);
    if (lane == 0) red[r0 + r][qw] = sq;
  }
  __syncthreads();
  if (t < OTOK) {
    float sm = red[t][0]+red[t][1]+red[t][2]+red[t][3];
    rs[t] = rsqrtf(sm/(float)DIN + 1e-5f);
  }
  __syncthreads();
#pragma unroll
  for (int r = 0; r < 16; ++r) {
    float val = v[r] * rs[r0 + r] * nwc;
    unsigned short hi = f2bf(val);
    yH[(r0 + r)*LDSY + c] = hi;
    yL[(r0 + r)*LDSY + c] = f2bf(val - bf2f(hi));
  }
  __syncthreads();
  int m = lane & 15, q = lane >> 4;
  {
    int jt = wave;                          // 8 waves <-> 8 j-tiles
    f32x4 acc0 = {0.f,0.f,0.f,0.f}, acc1 = {0.f,0.f,0.f,0.f};
#pragma unroll
    for (int kb = 0; kb < 8; ++kb) {
      bf16x8 bh, bl;
      if (kb < 4) { bh = pwh[kb]; bl = pwl[kb]; }
      else {
        size_t woff = (((size_t)jt*8 + kb)*64 + lane)*8;   // coalesced
        bh = *(const bf16x8*)(oH + woff);
        bl = *(const bf16x8*)(oL + woff);
      }
      int o0 = m*LDSY + kb*32 + q*8;
      int o1 = (16 + m)*LDSY + kb*32 + q*8;  // 16*LDSY ≡ 0 mod 32 dwords: same bank pattern
      bf16x8 a0h = ldfrag(yH, o0), a0l = ldfrag(yL, o0);
      bf16x8 a1h = ldfrag(yH, o1), a1l = ldfrag(yL, o1);
      acc0 = __builtin_amdgcn_mfma_f32_16x16x32_bf16(a0l, bh, acc0, 0, 0, 0);
      acc0 = __builtin_amdgcn_mfma_f32_16x16x32_bf16(a0h, bl, acc0, 0, 0, 0);
      acc0 = __builtin_amdgcn_mfma_f32_16x16x32_bf16(a0h, bh, acc0, 0, 0, 0);
      acc1 = __builtin_amdgcn_mfma_f32_16x16x32_bf16(a1l, bh, acc1, 0, 0, 0);
      acc1 = __builtin_amdgcn_mfma_f32_16x16x32_bf16(a1h, bl, acc1, 0, 0, 0);
      acc1 = __builtin_amdgcn_mfma_f32_16x16x32_bf16(a1h, bh, acc1, 0, 0, 0);
    }
    int j = jt*16 + m;                      // D col = lane&15
#pragma unroll
    for (int r = 0; r < 4; ++r) {
      int rr = q*4 + r;                     // frag 0 rows
      float val = acc0[r];
      unsigned short hi = f2bf(val);
      hsH[rr*LDSH + j] = hi;
      hsL[rr*LDSH + j] = f2bf(val - bf2f(hi));
      int l = l0 + rr;
      if (!doProj && l < LH) hout[((size_t)b*LH + l)*DIM + j] = val;
      int rr1 = 16 + q*4 + r;               // frag 1 rows
      float val1 = acc1[r];
      unsigned short hi1 = f2bf(val1);
      hsH[rr1*LDSH + j] = hi1;
      hsL[rr1*LDSH + j] = f2bf(val1 - bf2f(hi1));
      int l1 = l0 + rr1;
      if (!doProj && l1 < LH) hout[((size_t)b*LH + l1)*DIM + j] = val1;
    }
  }
  if (!doProj) return;
  __syncthreads();
  // ---- in_proj of next layer from the LDS h tile (32 rows, 8 waves)
#pragma unroll 2
  for (int jt = wave; jt < NJT; jt += 8) {
    size_t woff = (((size_t)jt*4)*64 + lane)*8;
    bf16x8 bh[4], bl[4];
#pragma unroll
    for (int kb = 0; kb < 4; ++kb) {
      bh[kb] = *(const bf16x8*)(wH + woff + (size_t)kb*64*8);  // coalesced
      bl[kb] = *(const bf16x8*)(wL + woff + (size_t)kb*64*8);
    }
    f32x4 acc0 = {0.f, 0.f, 0.f, 0.f}, acc1 = {0.f, 0.f, 0.f, 0.f};
#pragma unroll
    for (int kb = 0; kb < 4; ++kb) {
      int o0 = m*LDSH + kb*32 + q*8;
      int o1 = (16 + m)*LDSH + kb*32 + q*8;  // 16*LDSH ≡ 0 mod 32 dwords
      bf16x8 a0h = ldfrag(hsH, o0), a0l = ldfrag(hsL, o0);
      bf16x8 a1h = ldfrag(hsH, o1), a1l = ldfrag(hsL, o1);
      acc0 = __builtin_amdgcn_mfma_f32_16x16x32_bf16(a0l, bh[kb], acc0, 0, 0, 0);
      acc0 = __builtin_amdgcn_mfma_f32_16x16x32_bf16(a0h, bl[kb], acc0, 0, 0, 0);
      acc0 = __builtin_amdgcn_mfma_f32_16x16x32_bf16(a0h, bh[kb], acc0, 0, 0, 0);
      acc1 = __builtin_amdgcn_mfma_f32_16x16x32_bf16(a1l, bh[kb], acc1, 0, 0, 0);
      acc1 = __builtin_amdgcn_mfma_f32_16x16x32_bf16(a1h, bl[kb], acc1, 0, 0, 0);
      acc1 = __builtin_amdgcn_mfma_f32_16x16x32_bf16(a1h, bh[kb], acc1, 0, 0, 0);
    }
    int jj = jt*16 + m;
    if (jj < DPROJ) {
      bool isdt = (jj >= 640);
      float bias = isdt ? dtb[jj - 640] : 0.f;
#pragma unroll
      for (int r = 0; r < 4; ++r) {
        int tok = l0 + q*4 + r;
        if (tok < LH) {
          float vv = acc0[r];
          if (isdt) { vv += bias; vv = (vv > 20.f) ? vv : log1pf(__expf(vv)); }
          zx[((size_t)b*LH + tok)*DPROJ + jj] = vv;
        }
        int tok1 = l0 + 16 + q*4 + r;
        if (tok1 < LH) {
          float vv = acc1[r];
          if (isdt) { vv += bias; vv = (vv > 20.f) ? vv : log1pf(__expf(vv)); }
          zx[((size_t)b*LH + tok1)*DPROJ + jj] = vv;
        }
      }
    }
  }
}

// ---------------------------------------------------------------- final LN + head
__global__ void k_head(const float* __restrict__ h, const float* __restrict__ lnw,
                       const float* __restrict__ lnb, const float* __restrict__ hw,
                       const float* __restrict__ hb, float* __restrict__ out) {
  int b = blockIdx.x; int t = threadIdx.x;
  __shared__ float red[2];
  int wave = t >> 6, lane = t & 63;
  float v = h[((size_t)b*LH + LSEQ)*DIM + t];
  float s = v;
  for (int off = 32; off > 0; off >>= 1) s += __shfl_down(s, off);
  if (lane == 0) red[wave] = s;
  __syncthreads();
  float mean = (red[0]+red[1]) / (float)DIM;
  __syncthreads();
  float d = v - mean; float sq = d*d;
  for (int off = 32; off > 0; off >>= 1) sq += __shfl_down(sq, off);
  if (lane == 0) red[wave] = sq;
  __syncthreads();
  float var = (red[0]+red[1]) / (float)DIM;
  float cn = d*rsqrtf(var + 1e-5f)*lnw[t] + lnb[t];
  float dot = cn*hw[t];
  __syncthreads();
  for (int off = 32; off > 0; off >>= 1) dot += __shfl_down(dot, off);
  if (lane == 0) red[wave] = dot;
  __syncthreads();
  if (t == 0) out[b] = red[0]+red[1] + hb[0];
}

extern "C" void kernel_launch(void* const* d_in, const int* in_sizes, int n_in,
                              void* d_out, int out_size, void* d_ws, size_t ws_size,
                              hipStream_t stream) {
  const float* x     = (const float*)d_in[0];
  const float* w1    = (const float*)d_in[1];
  const float* b1    = (const float*)d_in[2];
  const float* w2    = (const float*)d_in[3];
  const float* b2    = (const float*)d_in[4];
  const float* cls   = (const float*)d_in[5];
  const float* inw   = (const float*)d_in[6];   // (4, 644, 128)
  const float* cw    = (const float*)d_in[7];   // (4, 384, 4)
  const float* cb    = (const float*)d_in[8];   // (4, 384)
  const float* dtb   = (const float*)d_in[9];   // (4, 4)
  const float* Alog  = (const float*)d_in[10];  // (4, 4)
  const float* Dh    = (const float*)d_in[11];  // (4, 4)
  const float* nw    = (const float*)d_in[12];  // (4, 256)
  const float* ow    = (const float*)d_in[13];  // (4, 128, 256)
  const float* lnw   = (const float*)d_in[14];
  const float* lnb   = (const float*)d_in[15];
  const float* hw    = (const float*)d_in[16];
  const float* hb    = (const float*)d_in[17];

  float* ws   = (float*)d_ws;
  float* zx   = ws;                                   // 10,535,840
  float* xbc  = zx + (size_t)BATCH*LH*DPROJ;          // 6,282,240
  float* ybuf = xbc + (size_t)BATCH*LH*CONVD;         // 4,194,304 (G aliases ybuf)
  float* G    = ybuf;
  float* Hin  = ybuf + 4194304;                       // 4,194,304
  float* dec  = Hin  + 4194304;                       // 1,024
  unsigned short* wH = (unsigned short*)(dec + 1024);      // 4*41*4*64*8 u16
  unsigned short* wL = wH + (size_t)DEPTH*NJT*4*64*8;      // same
  unsigned short* oH = wL + (size_t)DEPTH*NJT*4*64*8;      // 4*8*8*64*8 u16
  unsigned short* oL = oH + (size_t)DEPTH*8*8*64*8;        // same

  float* hout = (float*)d_out + 8;   // final h written directly into output

  k_cast_all<<<228, 256, 0, stream>>>(inw, ow, wH, wL, oH, oL);

  k_front_proj<<<BATCH*64, 512, 0, stream>>>(x, w1, b1, w2, b2, cls,
                                             wH, wL, dtb, zx);

  for (int i = 0; i < DEPTH; ++i) {
    int doProj = (i < DEPTH-1) ? 1 : 0;
    int nxt = doProj ? (i+1) : 0;
    k_conv<<<(int)(((long)BATCH*LH*(CONVD/4) + 255)/256), 256, 0, stream>>>(
        zx, cw + (size_t)i*CONVD*4, cb + (size_t)i*CONVD, xbc);
    k_chunk_state<<<BATCH*NH*NCH, 512, 0, stream>>>(zx, xbc, Alog + i*NH, G, dec);
    k_combine<<<BATCH*NH*4, 256, 0, stream>>>(G, dec, Hin);
    k_chunk_out<<<BATCH*NH*NCH, 512, 0, stream>>>(zx, xbc, Alog + i*NH, Hin, ybuf);
    k_out_fused<<<BATCH*64, 512, 0, stream>>>(
        ybuf, xbc, zx, Dh + i*NH, nw + (size_t)i*DIN,
        oH + (size_t)i*8*8*64*8, oL + (size_t)i*8*8*64*8,
        wH + (size_t)nxt*NJT*4*64*8, wL + (size_t)nxt*NJT*4*64*8,
        dtb + nxt*NH, hout, doProj);
  }

  k_head<<<BATCH, 128, 0, stream>>>(hout, lnw, lnb, hw, hb, (float*)d_out);
}

// Round 13
// 429.399 us; speedup vs baseline: 2.7836x; 1.0942x over previous
//
#include <hip/hip_runtime.h>
#include <math.h>

// Shapes (fixed by setup_inputs)
#define BATCH 8
#define TSEQ 2048
#define CIN 3
#define WIN 5
#define LSEQ 2044          // T - WIN + 1
#define LH 2045            // LSEQ + 1 (cls token appended)
#define DIM 128
#define DEPTH 4
#define DIN 256            // d_inner
#define NH 4               // heads
#define PDIM 64            // headdim
#define NSTATE 64          // d_state
#define CONVD 384          // d_inner + 2*d_state
#define DPROJ 644          // 2*d_inner + 2*d_state + nheads
#define NJT 41             // j-tiles of 16 (41*16 = 656 >= 644)
#define QC 64              // chunk length
#define NCH 32             // number of chunks
#define LDS2 68            // padded LDS row stride (shorts, 64-col frag buffers)
#define LDSY 268           // padded stride (shorts): 134 dwords ≡ 6 mod 32 -> frag reads bank-free
#define LDSH 140           // padded stride (shorts): 70 dwords ≡ 6 mod 32 -> bank-free, 8B-aligned rows
#define FTR 32             // tokens per k_front block
#define OTOK 32            // tokens per k_out_fused block (512-thread block, 8 waves)

typedef __attribute__((ext_vector_type(8))) short bf16x8;
typedef __attribute__((ext_vector_type(4))) float f32x4;
union Frag8 { bf16x8 v; uint2 u[2]; };

__device__ __forceinline__ float sigmoidf_(float x){ return 1.f/(1.f+__expf(-x)); }
__device__ __forceinline__ float siluf_(float x){ return x*sigmoidf_(x); }
__device__ __forceinline__ unsigned short f2bf(float f){   // RNE fp32->bf16
  unsigned int u = __float_as_uint(f);
  return (unsigned short)((u + 0x7FFFu + ((u >> 16) & 1u)) >> 16);
}
__device__ __forceinline__ float bf2f(unsigned short u){
  return __uint_as_float(((unsigned int)u) << 16);
}
__device__ __forceinline__ unsigned int pack2(float a, float b){  // [lo addr]=a
  return (unsigned int)f2bf(a) | ((unsigned int)f2bf(b) << 16);
}
__device__ __forceinline__ unsigned int pack2lo(float a, float b){
  float ra = a - bf2f(f2bf(a)), rb = b - bf2f(f2bf(b));
  return (unsigned int)f2bf(ra) | ((unsigned int)f2bf(rb) << 16);
}
__device__ __forceinline__ bf16x8 ldfrag(const unsigned short* base, int off){
  Frag8 f;
  f.u[0] = *(const uint2*)(base + off);
  f.u[1] = *(const uint2*)(base + off + 4);
  return f.v;
}

// ---------------------------------------------------------------- merged weight-cast
__global__ void __launch_bounds__(256) k_cast_all(
    const float* __restrict__ w, const float* __restrict__ ow,
    unsigned short* __restrict__ wH, unsigned short* __restrict__ wL,
    unsigned short* __restrict__ oH, unsigned short* __restrict__ oL) {
  int blk = blockIdx.x;
  if (blk < 164) {                            // inw: [ly][jt][kb][lane], 164*256 = 41984
    int gid = blk*256 + threadIdx.x;
    int lane = gid & 63;
    int kb = (gid >> 6) & 3;
    int jt = (gid >> 8) % NJT;
    int ly = gid / (NJT*4*64);
    int m = lane & 15, q = lane >> 4;
    int j = jt*16 + m;
    int k = kb*32 + q*8;
    unsigned short hi[8], lo[8];
    if (j < DPROJ) {
      const float* src = w + ((size_t)ly*DPROJ + j)*DIM + k;
#pragma unroll
      for (int i = 0; i < 8; ++i) {
        float v = src[i];
        hi[i] = f2bf(v);
        lo[i] = f2bf(v - bf2f(hi[i]));
      }
    } else {
#pragma unroll
      for (int i = 0; i < 8; ++i) { hi[i] = 0; lo[i] = 0; }
    }
    size_t dst = (size_t)gid*8;
    *(uint4*)(wH + dst) = *(const uint4*)hi;
    *(uint4*)(wL + dst) = *(const uint4*)lo;
  } else {                                    // ow: 64*256 = 16384
    int gid = (blk - 164)*256 + threadIdx.x;
    int lane = gid & 63;
    int kb = (gid >> 6) & 7;
    int jt = (gid >> 9) & 7;
    int ly = gid >> 12;
    int m = lane & 15, q = lane >> 4;
    int j = jt*16 + m;
    int k = kb*32 + q*8;
    const float* src = ow + ((size_t)ly*DIM + j)*DIN + k;
    unsigned short hi[8], lo[8];
#pragma unroll
    for (int i = 0; i < 8; ++i) {
      float v = src[i];
      hi[i] = f2bf(v);
      lo[i] = f2bf(v - bf2f(hi[i]));
    }
    size_t dst = (size_t)gid*8;
    *(uint4*)(oH + dst) = *(const uint4*)hi;
    *(uint4*)(oL + dst) = *(const uint4*)lo;
  }
}

// ---------------------------------------------------------------- front MLP + layer-0 in_proj
// R28 (R10-verified 494->474): in_proj fused; h tile in aliased bf16 LDS; cls inline.
__global__ void __launch_bounds__(512) k_front_proj(
    const float* __restrict__ x, const float* __restrict__ w1,
    const float* __restrict__ b1, const float* __restrict__ w2,
    const float* __restrict__ b2, const float* __restrict__ cls,
    const unsigned short* __restrict__ wH, const unsigned short* __restrict__ wL,
    const float* __restrict__ dtb, float* __restrict__ zx) {
  int t = threadIdx.x;
  int b = blockIdx.x >> 6;
  int c0 = (blockIdx.x & 63) * FTR;
  __shared__ __align__(16) float pool[108 + 2176 + 4096 + 8192];
  float* xs   = pool;
  float* w1s  = pool + 108;
  float* h1s  = pool + 108 + 2176;           // [32][128]
  float* part = pool + 108 + 2176 + 4096;    // [32][128][2]
  unsigned short* hsH = (unsigned short*)pool;
  unsigned short* hsL = hsH + 32*LDSH;       // aliases dead region by phase 3
  for (int i = t; i < (FTR+4)*CIN; i += 512) {
    int row = c0 + i/3, ch = i - (i/3)*3;
    xs[i] = (row < TSEQ) ? x[(size_t)b*TSEQ*CIN + (size_t)row*CIN + ch] : 0.f;
  }
  for (int i = t; i < DIM*15; i += 512) {
    int j = i/15, k = i - j*15;
    w1s[j*17+k] = w1[i];
  }
  __syncthreads();
  {
    int j = t & 127, rh = t >> 7;            // rh 0..3 -> 8 rows each
    float bias = b1[j];
    const float* wr = &w1s[j*17];
    for (int r = rh*8; r < rh*8+8; ++r) {
      float a = bias;
#pragma unroll
      for (int k = 0; k < 15; ++k) a += xs[r*3+k]*wr[k];
      h1s[r*128 + j] = 0.5f*a*(1.f + erff(a*0.70710678118654752f));  // exact gelu
    }
  }
  __syncthreads();
  {
    int j = t & 127, z = t >> 7;             // z 0..3
    int hf = z & 1, rh2 = z >> 1;            // k-half, row-half (16 rows)
    float4 wv[16];
    const float4* w2r = (const float4*)(w2 + (size_t)j*DIM + hf*64);
#pragma unroll
    for (int k4 = 0; k4 < 16; ++k4) wv[k4] = w2r[k4];
#pragma unroll 2
    for (int r = rh2*16; r < rh2*16+16; ++r) {
      const float4* hr = (const float4*)&h1s[r*128 + hf*64];
      float acc = 0.f;
#pragma unroll
      for (int k4 = 0; k4 < 16; ++k4) {
        float4 hv = hr[k4];
        acc += wv[k4].x*hv.x + wv[k4].y*hv.y + wv[k4].z*hv.z + wv[k4].w*hv.w;
      }
      part[(r*128 + j)*2 + hf] = acc;
    }
  }
  __syncthreads();
  {
    int c = t & 127, rh = t >> 7;            // 8 rows each
    float bias = b2[c];
    for (int r = rh*8; r < rh*8+8; ++r) {
      int l = c0 + r;
      float val;
      if (l < LSEQ)       val = part[(r*128 + c)*2] + part[(r*128 + c)*2 + 1] + bias;
      else if (l == LSEQ) val = cls[c];
      else                val = 0.f;
      unsigned short hi = f2bf(val);
      hsH[r*LDSH + c] = hi;
      hsL[r*LDSH + c] = f2bf(val - bf2f(hi));
    }
  }
  __syncthreads();
  int wave = t >> 6, lane = t & 63;
  int m = lane & 15, q = lane >> 4;
#pragma unroll 2
  for (int jt = wave; jt < NJT; jt += 8) {
    size_t woff = (((size_t)jt*4)*64 + lane)*8;
    bf16x8 bh[4], bl[4];
#pragma unroll
    for (int kb = 0; kb < 4; ++kb) {
      bh[kb] = *(const bf16x8*)(wH + woff + (size_t)kb*64*8);  // coalesced
      bl[kb] = *(const bf16x8*)(wL + woff + (size_t)kb*64*8);
    }
    f32x4 acc0 = {0.f, 0.f, 0.f, 0.f}, acc1 = {0.f, 0.f, 0.f, 0.f};
#pragma unroll
    for (int kb = 0; kb < 4; ++kb) {
      int o0 = m*LDSH + kb*32 + q*8;
      int o1 = (16 + m)*LDSH + kb*32 + q*8;  // 16*LDSH ≡ 0 mod 32 dwords
      bf16x8 a0h = ldfrag(hsH, o0), a0l = ldfrag(hsL, o0);
      bf16x8 a1h = ldfrag(hsH, o1), a1l = ldfrag(hsL, o1);
      acc0 = __builtin_amdgcn_mfma_f32_16x16x32_bf16(a0l, bh[kb], acc0, 0, 0, 0);
      acc0 = __builtin_amdgcn_mfma_f32_16x16x32_bf16(a0h, bl[kb], acc0, 0, 0, 0);
      acc0 = __builtin_amdgcn_mfma_f32_16x16x32_bf16(a0h, bh[kb], acc0, 0, 0, 0);
      acc1 = __builtin_amdgcn_mfma_f32_16x16x32_bf16(a1l, bh[kb], acc1, 0, 0, 0);
      acc1 = __builtin_amdgcn_mfma_f32_16x16x32_bf16(a1h, bl[kb], acc1, 0, 0, 0);
      acc1 = __builtin_amdgcn_mfma_f32_16x16x32_bf16(a1h, bh[kb], acc1, 0, 0, 0);
    }
    int jj = jt*16 + m;
    if (jj < DPROJ) {
      bool isdt = (jj >= 640);
      float bias = isdt ? dtb[jj - 640] : 0.f;
#pragma unroll
      for (int r = 0; r < 4; ++r) {
        int tok = c0 + q*4 + r;
        if (tok < LH) {
          float vv = acc0[r];
          if (isdt) { vv += bias; vv = (vv > 20.f) ? vv : log1pf(__expf(vv)); }
          zx[((size_t)b*LH + tok)*DPROJ + jj] = vv;
        }
        int tok1 = c0 + 16 + q*4 + r;
        if (tok1 < LH) {
          float vv = acc1[r];
          if (isdt) { vv += bias; vv = (vv > 20.f) ? vv : log1pf(__expf(vv)); }
          zx[((size_t)b*LH + tok1)*DPROJ + jj] = vv;
        }
      }
    }
  }
}

// ---------------------------------------------------------------- chunked SSD, phase A
// R31: conv+silu fused IN (streaming rolling-window form; R9 data showed this
// kernel's streamed conv costs only ~+3 us — the R9 regression was chunk_out's
// gather form, which stays on the xbc path). This kernel now PRODUCES xbc:
//   x-panel (its head's 64 ch): computed for LDS + stored (unique writer).
//   B-panel: computed by all blocks for LDS; hd==0 stores.
//   C-panel: hd==1 blocks compute + store (store-only).
// Conv FP order identical to old k_conv (taps ascending) -> bit-identical xbc.
// k_conv dispatch deleted (4 fewer launches).
__global__ void __launch_bounds__(512, 4) k_chunk_state(
    const float* __restrict__ zx, const float* __restrict__ cw,
    const float* __restrict__ cb, const float* __restrict__ A_log,
    float* __restrict__ G, float* __restrict__ dec, float* __restrict__ xbc) {
  int blk = blockIdx.x;
  int c = blk & (NCH-1), hd = (blk >> 5) & 3, b = blk >> 7;
  int t0 = c*QC;
  int tid = threadIdx.x;
  int wave = tid >> 6, lane = tid & 63;
  int wr = wave & 3, wh = wave >> 2;
  int m = lane & 15, q = lane >> 4;
  float A = -__expf(A_log[hd]);
  __shared__ __align__(16) unsigned short BcH[QC*LDS2], BcL[QC*LDS2]; // [n][s]
  __shared__ __align__(16) unsigned short XtH[QC*LDS2], XtL[QC*LDS2]; // [p][s]
  __shared__ float coef[QC];
  float dtv = 0.f;
  if (tid < 64) {
    int tg = t0 + tid;
    dtv = (tg < LH) ? zx[((size_t)b*LH + tg)*DPROJ + 640 + hd] : 0.f;
  }
  // ---- streaming conv: thread owns (panel, channel, 16-row quarter)
  int chIdx = tid & 127, half = tid >> 7;    // half 0..3 -> rows 16 each
  bool isB = (chIdx >= 64);
  int n = chIdx & 63;
  int xch = isB ? (DIN + n) : (hd*PDIM + n); // xbc channel
  int col = 256 + xch;                       // zx column
  const float4 wv4 = *(const float4*)(cw + xch*4);
  float bias = cb[xch];
  int s0 = half*16;
  float bb[16];                              // B-panel conv values (pre-coef)
  {
    float x3, x2, x1;
    int t3 = t0 + s0 - 3, t2_ = t0 + s0 - 2, t1_ = t0 + s0 - 1;
    x3 = (t3 >= 0 && t3 < LH) ? zx[((size_t)b*LH + t3)*DPROJ + col] : 0.f;
    x2 = (t2_ >= 0 && t2_ < LH) ? zx[((size_t)b*LH + t2_)*DPROJ + col] : 0.f;
    x1 = (t1_ >= 0 && t1_ < LH) ? zx[((size_t)b*LH + t1_)*DPROJ + col] : 0.f;
    float prev = 0.f;
#pragma unroll
    for (int i = 0; i < 16; ++i) {
      int s = s0 + i;
      int tg = t0 + s;
      float x0 = (tg < LH) ? zx[((size_t)b*LH + tg)*DPROJ + col] : 0.f;
      float a = bias;
      a += x3*wv4.x; a += x2*wv4.y; a += x1*wv4.z; a += x0*wv4.w;
      float out = (tg < LH) ? siluf_(a) : 0.f;
      // global xbc store: x-panel always; B-panel only hd==0
      if (tg < LH && (!isB || hd == 0))
        xbc[((size_t)b*LH + tg)*CONVD + xch] = out;
      if (isB) {
        bb[i] = out;                         // pack after coef is ready
      } else {
        if (i & 1) {                         // x-panel: straight to LDS in pairs
          int o = n*LDS2 + (s - 1);
          *(unsigned int*)(XtH + o) = pack2(prev, out);
          *(unsigned int*)(XtL + o) = pack2lo(prev, out);
        } else prev = out;
      }
      x3 = x2; x2 = x1; x1 = x0;
    }
  }
  // ---- C-panel (store-only) on hd==1 blocks: ch = tid&63, 8-row octant
  if (hd == 1) {
    int cc = tid & 63, oct = tid >> 6;       // oct 0..7
    int xch2 = DIN + NSTATE + cc;            // xbc channel 320+cc
    int col2 = 256 + xch2;                   // zx col 576+cc
    const float4 w2v = *(const float4*)(cw + xch2*4);
    float bias2 = cb[xch2];
    int s0c = oct*8;
    float x3, x2, x1;
    int t3 = t0 + s0c - 3, t2_ = t0 + s0c - 2, t1_ = t0 + s0c - 1;
    x3 = (t3 >= 0 && t3 < LH) ? zx[((size_t)b*LH + t3)*DPROJ + col2] : 0.f;
    x2 = (t2_ >= 0 && t2_ < LH) ? zx[((size_t)b*LH + t2_)*DPROJ + col2] : 0.f;
    x1 = (t1_ >= 0 && t1_ < LH) ? zx[((size_t)b*LH + t1_)*DPROJ + col2] : 0.f;
#pragma unroll
    for (int i = 0; i < 8; ++i) {
      int tg = t0 + s0c + i;
      float x0 = (tg < LH) ? zx[((size_t)b*LH + tg)*DPROJ + col2] : 0.f;
      float a = bias2;
      a += x3*w2v.x; a += x2*w2v.y; a += x1*w2v.z; a += x0*w2v.w;
      if (tg < LH) xbc[((size_t)b*LH + tg)*CONVD + xch2] = siluf_(a);
      x3 = x2; x2 = x1; x1 = x0;
    }
  }
  if (tid < 64) {
    float s = dtv;
#pragma unroll
    for (int off = 1; off < 64; off <<= 1) {
      float u = __shfl_up(s, off);
      if (tid >= off) s += u;
    }
    float cq = __shfl(s, 63);
    coef[tid] = __expf(A*(cq - s)) * dtv;
    if (tid == 63) dec[blk] = __expf(A * s);
  }
  __syncthreads();
  // B-panel: multiply by coef, pack to LDS
  if (isB) {
#pragma unroll
    for (int j = 0; j < 8; ++j) {
      int s = s0 + 2*j;
      float b0 = bb[2*j]   * coef[s];
      float b1 = bb[2*j+1] * coef[s+1];
      int o = n*LDS2 + s;
      *(unsigned int*)(BcH + o) = pack2(b0, b1);
      *(unsigned int*)(BcL + o) = pack2lo(b0, b1);
    }
  }
  __syncthreads();
  bf16x8 ah[2], al[2];
#pragma unroll
  for (int kc = 0; kc < 2; ++kc) {
    int off = (wr*16 + m)*LDS2 + kc*32 + q*8;
    ah[kc] = ldfrag(BcH, off);
    al[kc] = ldfrag(BcL, off);
  }
#pragma unroll
  for (int nth = 0; nth < 2; ++nth) {
    int nt = wh*2 + nth;
    f32x4 acc = {0.f,0.f,0.f,0.f};
#pragma unroll
    for (int kc = 0; kc < 2; ++kc) {
      int off = (nt*16 + m)*LDS2 + kc*32 + q*8;
      bf16x8 xh = ldfrag(XtH, off), xl = ldfrag(XtL, off);
      acc = __builtin_amdgcn_mfma_f32_16x16x32_bf16(al[kc], xh, acc, 0, 0, 0);
      acc = __builtin_amdgcn_mfma_f32_16x16x32_bf16(ah[kc], xl, acc, 0, 0, 0);
      acc = __builtin_amdgcn_mfma_f32_16x16x32_bf16(ah[kc], xh, acc, 0, 0, 0);
    }
    int p = nt*16 + m;
#pragma unroll
    for (int r = 0; r < 4; ++r) {
      int n2 = wr*16 + q*4 + r;
      G[(size_t)blk*4096 + n2*64 + p] = acc[r];
    }
  }
}

// ---------------------------------------------------------------- phase B: inter-chunk
// R24: 4-deep rotating load pipeline. (R11's last-block fusion regressed 2.5x —
// keep the 128-block kernel.)
__global__ void __launch_bounds__(256) k_combine(
    const float* __restrict__ G, const float* __restrict__ dec, float* __restrict__ Hin) {
  int bh = blockIdx.x >> 2, esp = blockIdx.x & 3;
  int e = esp*1024 + threadIdx.x*4;
  size_t base0 = (size_t)bh*NCH*4096 + e;
  float4 gq[4]; float dq[4];
#pragma unroll
  for (int k = 0; k < 4; ++k) {
    gq[k] = *(const float4*)(G + base0 + (size_t)k*4096);
    dq[k] = dec[bh*NCH + k];
  }
  float4 H = make_float4(0.f,0.f,0.f,0.f);
#pragma unroll 4
  for (int c = 0; c < NCH; ++c) {
    int slot = c & 3;
    float4 g = gq[slot]; float d = dq[slot];
    if (c + 4 < NCH) {
      gq[slot] = *(const float4*)(G + base0 + (size_t)(c+4)*4096);
      dq[slot] = dec[bh*NCH + c + 4];
    }
    *(float4*)(Hin + base0 + (size_t)c*4096) = H;   // carry-in for chunk c
    H.x = H.x*d + g.x; H.y = H.y*d + g.y; H.z = H.z*d + g.z; H.w = H.w*d + g.w;
  }
}

// ---------------------------------------------------------------- phase C: chunk output
// R30 (R12-verified): 512 threads (8 waves = wr x wh), same LDS, R24 prefetches.
// Reads xbc (now produced by k_chunk_state) — staging unchanged.
__global__ void __launch_bounds__(512, 8) k_chunk_out(
    const float* __restrict__ zx, const float* __restrict__ xbc,
    const float* __restrict__ A_log, const float* __restrict__ Hin,
    float* __restrict__ y) {
  int blk = blockIdx.x;
  int c = blk & (NCH-1), hd = (blk >> 5) & 3, b = blk >> 7;
  int t0 = c*QC;
  int tid = threadIdx.x;
  int wave = tid >> 6, lane = tid & 63;
  int wr = wave & 3, wh = wave >> 2;
  int m = lane & 15, q = lane >> 4;
  float A = -__expf(A_log[hd]);
  __shared__ __align__(16) unsigned short P0H[QC*LDS2], P0L[QC*LDS2]; // C, then mask
  __shared__ __align__(16) unsigned short P1H[QC*LDS2], P1L[QC*LDS2]; // B, HinT, Xt
  __shared__ float cum[QC], dts[QC], pref[QC];
  float dtv = 0.f;
  if (tid < 64) {
    int tg = t0 + tid;
    dtv = (tg < LH) ? zx[((size_t)b*LH + tg)*DPROJ + 640 + hd] : 0.f;
  }
  float pbv[8], pcv[8];
#pragma unroll
  for (int it = 0; it < 4; ++it) {
    int i = tid + it*512;
    int s = i >> 5, j2 = (i & 31)*2;
    int tg = t0 + s;
    float b0 = 0.f, b1 = 0.f, c0_ = 0.f, c1_ = 0.f;
    if (tg < LH) {
      size_t row = ((size_t)b*LH + tg)*CONVD;
      float2 bv = *(const float2*)(xbc + row + DIN + j2);
      float2 cv = *(const float2*)(xbc + row + DIN + NSTATE + j2);
      b0 = bv.x; b1 = bv.y; c0_ = cv.x; c1_ = cv.y;
    }
    pbv[it*2] = b0; pbv[it*2+1] = b1; pcv[it*2] = c0_; pcv[it*2+1] = c1_;
  }
  size_t hbase = (size_t)blk*4096;
  float hv[8];
#pragma unroll
  for (int it = 0; it < 4; ++it) {
    int i = tid + it*512;
    int p = i & 63, n2 = (i >> 6)*2;
    hv[it*2]   = Hin[hbase + (size_t)n2*64 + p];
    hv[it*2+1] = Hin[hbase + (size_t)(n2+1)*64 + p];
  }
  if (tid < 64) {
    float s = dtv;
#pragma unroll
    for (int off = 1; off < 64; off <<= 1) {
      float u = __shfl_up(s, off);
      if (tid >= off) s += u;
    }
    dts[tid] = dtv; cum[tid] = s; pref[tid] = __expf(A*s);
  }
#pragma unroll
  for (int it = 0; it < 4; ++it) {
    int i = tid + it*512;
    int s = i >> 5, j2 = (i & 31)*2;
    int o = s*LDS2 + j2;
    *(unsigned int*)(P1H + o) = pack2(pbv[it*2], pbv[it*2+1]);
    *(unsigned int*)(P1L + o) = pack2lo(pbv[it*2], pbv[it*2+1]);
    *(unsigned int*)(P0H + o) = pack2(pcv[it*2], pcv[it*2+1]);
    *(unsigned int*)(P0L + o) = pack2lo(pcv[it*2], pcv[it*2+1]);
  }
  __syncthreads();                                    // A
  bf16x8 ch[2], cl[2];
#pragma unroll
  for (int kc = 0; kc < 2; ++kc) {
    int off = (wr*16 + m)*LDS2 + kc*32 + q*8;
    ch[kc] = ldfrag(P0H, off);
    cl[kc] = ldfrag(P0L, off);
  }
  f32x4 sacc[2];
#pragma unroll
  for (int nth = 0; nth < 2; ++nth) {
    int nt = wh*2 + nth;
    f32x4 a1 = {0.f,0.f,0.f,0.f};
#pragma unroll
    for (int kc = 0; kc < 2; ++kc) {
      int off = (nt*16 + m)*LDS2 + kc*32 + q*8;
      bf16x8 bh = ldfrag(P1H, off), bl = ldfrag(P1L, off);
      a1 = __builtin_amdgcn_mfma_f32_16x16x32_bf16(cl[kc], bh, a1, 0, 0, 0);
      a1 = __builtin_amdgcn_mfma_f32_16x16x32_bf16(ch[kc], bl, a1, 0, 0, 0);
      a1 = __builtin_amdgcn_mfma_f32_16x16x32_bf16(ch[kc], bh, a1, 0, 0, 0);
    }
    sacc[nth] = a1;
  }
  __syncthreads();                                    // B: C,B dead
  float xv[8];
#pragma unroll
  for (int it = 0; it < 4; ++it) {
    int i = tid + it*512;
    int p = i & 63, s2 = (i >> 6)*2;
    int tg = t0 + s2;
    xv[it*2]   = (tg < LH)   ? xbc[((size_t)b*LH + tg)*CONVD + hd*PDIM + p]   : 0.f;
    xv[it*2+1] = (tg+1 < LH) ? xbc[((size_t)b*LH + tg+1)*CONVD + hd*PDIM + p] : 0.f;
  }
#pragma unroll
  for (int nth = 0; nth < 2; ++nth) {
    int nt = wh*2 + nth;
    int s = nt*16 + m;
#pragma unroll
    for (int r = 0; r < 4; ++r) {
      int t = wr*16 + q*4 + r;
      float mv = 0.f;
      if (s <= t) mv = sacc[nth][r] * __expf(A*(cum[t] - cum[s])) * dts[s];
      unsigned short hi = f2bf(mv);
      P0H[t*LDS2 + s] = hi;
      P0L[t*LDS2 + s] = f2bf(mv - bf2f(hi));
    }
  }
#pragma unroll
  for (int it = 0; it < 4; ++it) {
    int i = tid + it*512;
    int p = i & 63, n2 = (i >> 6)*2;
    int o = p*LDS2 + n2;
    *(unsigned int*)(P1H + o) = pack2(hv[it*2], hv[it*2+1]);
    *(unsigned int*)(P1L + o) = pack2lo(hv[it*2], hv[it*2+1]);
  }
  __syncthreads();                                    // C
  f32x4 y2a[2];
#pragma unroll
  for (int nth = 0; nth < 2; ++nth) {
    int nt = wh*2 + nth;
    f32x4 a2 = {0.f,0.f,0.f,0.f};
#pragma unroll
    for (int kc = 0; kc < 2; ++kc) {
      int off = (nt*16 + m)*LDS2 + kc*32 + q*8;
      bf16x8 th = ldfrag(P1H, off), tl = ldfrag(P1L, off);
      a2 = __builtin_amdgcn_mfma_f32_16x16x32_bf16(cl[kc], th, a2, 0, 0, 0);
      a2 = __builtin_amdgcn_mfma_f32_16x16x32_bf16(ch[kc], tl, a2, 0, 0, 0);
      a2 = __builtin_amdgcn_mfma_f32_16x16x32_bf16(ch[kc], th, a2, 0, 0, 0);
    }
    y2a[nth] = a2;
  }
  bf16x8 mh[2], ml[2];
#pragma unroll
  for (int kc = 0; kc < 2; ++kc) {
    int off = (wr*16 + m)*LDS2 + kc*32 + q*8;
    mh[kc] = ldfrag(P0H, off);
    ml[kc] = ldfrag(P0L, off);
  }
  __syncthreads();                                    // D: Hin dead
#pragma unroll
  for (int it = 0; it < 4; ++it) {
    int i = tid + it*512;
    int p = i & 63, s2 = (i >> 6)*2;
    int o = p*LDS2 + s2;
    *(unsigned int*)(P1H + o) = pack2(xv[it*2], xv[it*2+1]);
    *(unsigned int*)(P1L + o) = pack2lo(xv[it*2], xv[it*2+1]);
  }
  __syncthreads();                                    // E
#pragma unroll
  for (int nth = 0; nth < 2; ++nth) {
    int nt = wh*2 + nth;
    f32x4 a1 = {0.f,0.f,0.f,0.f};
#pragma unroll
    for (int kc = 0; kc < 2; ++kc) {
      int off = (nt*16 + m)*LDS2 + kc*32 + q*8;
      bf16x8 th = ldfrag(P1H, off), tl = ldfrag(P1L, off);
      a1 = __builtin_amdgcn_mfma_f32_16x16x32_bf16(ml[kc], th, a1, 0, 0, 0);
      a1 = __builtin_amdgcn_mfma_f32_16x16x32_bf16(mh[kc], tl, a1, 0, 0, 0);
      a1 = __builtin_amdgcn_mfma_f32_16x16x32_bf16(mh[kc], th, a1, 0, 0, 0);
    }
    int p = nt*16 + m;
#pragma unroll
    for (int r = 0; r < 4; ++r) {
      int t = wr*16 + q*4 + r, tg = t0 + t;
      if (tg < LH)
        y[((size_t)b*LH + tg)*DIN + hd*PDIM + p] = a1[r] + pref[t]*y2a[nth][r];
    }
  }
}

// ---------------------------------------------------------------- gate+rmsnorm+out_proj
// FUSED with next layer's in_proj. R22 512-thread OTOK=32; R23 weight prefetch.
__global__ void __launch_bounds__(512, 4) k_out_fused(
    const float* __restrict__ y, const float* __restrict__ xbc,
    float* __restrict__ zx, const float* __restrict__ Dh,
    const float* __restrict__ nw, const unsigned short* __restrict__ oH,
    const unsigned short* __restrict__ oL,
    const unsigned short* __restrict__ wH, const unsigned short* __restrict__ wL,
    const float* __restrict__ dtb, float* __restrict__ hout, int doProj) {
  int b = blockIdx.x >> 6;
  int l0 = (blockIdx.x & 63) * OTOK;
  int t = threadIdx.x;
  __shared__ __align__(16) unsigned short yH[OTOK*LDSY], yL[OTOK*LDSY];
  __shared__ __align__(16) unsigned short hsH[OTOK*LDSH], hsL[OTOK*LDSH];
  __shared__ float red[OTOK][4];
  __shared__ float rs[OTOK];
  int wave = t >> 6, lane = t & 63;
  bf16x8 pwh[4], pwl[4];
#pragma unroll
  for (int kb = 0; kb < 4; ++kb) {
    size_t woff = (((size_t)wave*8 + kb)*64 + lane)*8;
    pwh[kb] = *(const bf16x8*)(oH + woff);
    pwl[kb] = *(const bf16x8*)(oL + woff);
  }
  int c = t & 255;
  int rh = t >> 8;           // row-half: 0 -> rows 0..15, 1 -> rows 16..31
  int r0 = rh*16;
  int hd = c >> 6;
  float dcoef = Dh[hd];
  float nwc = nw[c];
  float v[16];
#pragma unroll
  for (int r = 0; r < 16; ++r) {
    int l = l0 + r0 + r;
    float val = 0.f;
    if (l < LH) {
      size_t row = (size_t)b*LH + l;
      float ys = y[row*DIN + c];
      float xh = xbc[row*CONVD + c];
      float z  = zx[row*DPROJ + c];
      val = (ys + dcoef*xh) * siluf_(z);
    }
    v[r] = val;
  }
  int qw = wave & 3;         // channel-quarter within the row-half
#pragma unroll
  for (int r = 0; r < 16; ++r) {
    float sq = v[r]*v[r];
    for (int off = 32; off > 0; off >>= 1) sq += __shfl_down(sq, off);
    if (lane == 0) red[r0 + r][qw] = sq;
  }
  __syncthreads();
  if (t < OTOK) {
    float sm = red[t][0]+red[t][1]+red[t][2]+red[t][3];
    rs[t] = rsqrtf(sm/(float)DIN + 1e-5f);
  }
  __syncthreads();
#pragma unroll
  for (int r = 0; r < 16; ++r) {
    float val = v[r] * rs[r0 + r] * nwc;
    unsigned short hi = f2bf(val);
    yH[(r0 + r)*LDSY + c] = hi;
    yL[(r0 + r)*LDSY + c] = f2bf(val - bf2f(hi));
  }
  __syncthreads();
  int m = lane & 15, q = lane >> 4;
  {
    int jt = wave;                          // 8 waves <-> 8 j-tiles
    f32x4 acc0 = {0.f,0.f,0.f,0.f}, acc1 = {0.f,0.f,0.f,0.f};
#pragma unroll
    for (int kb = 0; kb < 8; ++kb) {
      bf16x8 bh, bl;
      if (kb < 4) { bh = pwh[kb]; bl = pwl[kb]; }
      else {
        size_t woff = (((size_t)jt*8 + kb)*64 + lane)*8;   // coalesced
        bh = *(const bf16x8*)(oH + woff);
        bl = *(const bf16x8*)(oL + woff);
      }
      int o0 = m*LDSY + kb*32 + q*8;
      int o1 = (16 + m)*LDSY + kb*32 + q*8;  // 16*LDSY ≡ 0 mod 32 dwords: same bank pattern
      bf16x8 a0h = ldfrag(yH, o0), a0l = ldfrag(yL, o0);
      bf16x8 a1h = ldfrag(yH, o1), a1l = ldfrag(yL, o1);
      acc0 = __builtin_amdgcn_mfma_f32_16x16x32_bf16(a0l, bh, acc0, 0, 0, 0);
      acc0 = __builtin_amdgcn_mfma_f32_16x16x32_bf16(a0h, bl, acc0, 0, 0, 0);
      acc0 = __builtin_amdgcn_mfma_f32_16x16x32_bf16(a0h, bh, acc0, 0, 0, 0);
      acc1 = __builtin_amdgcn_mfma_f32_16x16x32_bf16(a1l, bh, acc1, 0, 0, 0);
      acc1 = __builtin_amdgcn_mfma_f32_16x16x32_bf16(a1h, bl, acc1, 0, 0, 0);
      acc1 = __builtin_amdgcn_mfma_f32_16x16x32_bf16(a1h, bh, acc1, 0, 0, 0);
    }
    int j = jt*16 + m;                      // D col = lane&15
#pragma unroll
    for (int r = 0; r < 4; ++r) {
      int rr = q*4 + r;                     // frag 0 rows
      float val = acc0[r];
      unsigned short hi = f2bf(val);
      hsH[rr*LDSH + j] = hi;
      hsL[rr*LDSH + j] = f2bf(val - bf2f(hi));
      int l = l0 + rr;
      if (!doProj && l < LH) hout[((size_t)b*LH + l)*DIM + j] = val;
      int rr1 = 16 + q*4 + r;               // frag 1 rows
      float val1 = acc1[r];
      unsigned short hi1 = f2bf(val1);
      hsH[rr1*LDSH + j] = hi1;
      hsL[rr1*LDSH + j] = f2bf(val1 - bf2f(hi1));
      int l1 = l0 + rr1;
      if (!doProj && l1 < LH) hout[((size_t)b*LH + l1)*DIM + j] = val1;
    }
  }
  if (!doProj) return;
  __syncthreads();
  // ---- in_proj of next layer from the LDS h tile (32 rows, 8 waves)
#pragma unroll 2
  for (int jt = wave; jt < NJT; jt += 8) {
    size_t woff = (((size_t)jt*4)*64 + lane)*8;
    bf16x8 bh[4], bl[4];
#pragma unroll
    for (int kb = 0; kb < 4; ++kb) {
      bh[kb] = *(const bf16x8*)(wH + woff + (size_t)kb*64*8);  // coalesced
      bl[kb] = *(const bf16x8*)(wL + woff + (size_t)kb*64*8);
    }
    f32x4 acc0 = {0.f, 0.f, 0.f, 0.f}, acc1 = {0.f, 0.f, 0.f, 0.f};
#pragma unroll
    for (int kb = 0; kb < 4; ++kb) {
      int o0 = m*LDSH + kb*32 + q*8;
      int o1 = (16 + m)*LDSH + kb*32 + q*8;  // 16*LDSH ≡ 0 mod 32 dwords
      bf16x8 a0h = ldfrag(hsH, o0), a0l = ldfrag(hsL, o0);
      bf16x8 a1h = ldfrag(hsH, o1), a1l = ldfrag(hsL, o1);
      acc0 = __builtin_amdgcn_mfma_f32_16x16x32_bf16(a0l, bh[kb], acc0, 0, 0, 0);
      acc0 = __builtin_amdgcn_mfma_f32_16x16x32_bf16(a0h, bl[kb], acc0, 0, 0, 0);
      acc0 = __builtin_amdgcn_mfma_f32_16x16x32_bf16(a0h, bh[kb], acc0, 0, 0, 0);
      acc1 = __builtin_amdgcn_mfma_f32_16x16x32_bf16(a1l, bh[kb], acc1, 0, 0, 0);
      acc1 = __builtin_amdgcn_mfma_f32_16x16x32_bf16(a1h, bl[kb], acc1, 0, 0, 0);
      acc1 = __builtin_amdgcn_mfma_f32_16x16x32_bf16(a1h, bh[kb], acc1, 0, 0, 0);
    }
    int jj = jt*16 + m;
    if (jj < DPROJ) {
      bool isdt = (jj >= 640);
      float bias = isdt ? dtb[jj - 640] : 0.f;
#pragma unroll
      for (int r = 0; r < 4; ++r) {
        int tok = l0 + q*4 + r;
        if (tok < LH) {
          float vv = acc0[r];
          if (isdt) { vv += bias; vv = (vv > 20.f) ? vv : log1pf(__expf(vv)); }
          zx[((size_t)b*LH + tok)*DPROJ + jj] = vv;
        }
        int tok1 = l0 + 16 + q*4 + r;
        if (tok1 < LH) {
          float vv = acc1[r];
          if (isdt) { vv += bias; vv = (vv > 20.f) ? vv : log1pf(__expf(vv)); }
          zx[((size_t)b*LH + tok1)*DPROJ + jj] = vv;
        }
      }
    }
  }
}

// ---------------------------------------------------------------- final LN + head
__global__ void k_head(const float* __restrict__ h, const float* __restrict__ lnw,
                       const float* __restrict__ lnb, const float* __restrict__ hw,
                       const float* __restrict__ hb, float* __restrict__ out) {
  int b = blockIdx.x; int t = threadIdx.x;
  __shared__ float red[2];
  int wave = t >> 6, lane = t & 63;
  float v = h[((size_t)b*LH + LSEQ)*DIM + t];
  float s = v;
  for (int off = 32; off > 0; off >>= 1) s += __shfl_down(s, off);
  if (lane == 0) red[wave] = s;
  __syncthreads();
  float mean = (red[0]+red[1]) / (float)DIM;
  __syncthreads();
  float d = v - mean; float sq = d*d;
  for (int off = 32; off > 0; off >>= 1) sq += __shfl_down(sq, off);
  if (lane == 0) red[wave] = sq;
  __syncthreads();
  float var = (red[0]+red[1]) / (float)DIM;
  float cn = d*rsqrtf(var + 1e-5f)*lnw[t] + lnb[t];
  float dot = cn*hw[t];
  __syncthreads();
  for (int off = 32; off > 0; off >>= 1) dot += __shfl_down(dot, off);
  if (lane == 0) red[wave] = dot;
  __syncthreads();
  if (t == 0) out[b] = red[0]+red[1] + hb[0];
}

extern "C" void kernel_launch(void* const* d_in, const int* in_sizes, int n_in,
                              void* d_out, int out_size, void* d_ws, size_t ws_size,
                              hipStream_t stream) {
  const float* x     = (const float*)d_in[0];
  const float* w1    = (const float*)d_in[1];
  const float* b1    = (const float*)d_in[2];
  const float* w2    = (const float*)d_in[3];
  const float* b2    = (const float*)d_in[4];
  const float* cls   = (const float*)d_in[5];
  const float* inw   = (const float*)d_in[6];   // (4, 644, 128)
  const float* cw    = (const float*)d_in[7];   // (4, 384, 4)
  const float* cb    = (const float*)d_in[8];   // (4, 384)
  const float* dtb   = (const float*)d_in[9];   // (4, 4)
  const float* Alog  = (const float*)d_in[10];  // (4, 4)
  const float* Dh    = (const float*)d_in[11];  // (4, 4)
  const float* nw    = (const float*)d_in[12];  // (4, 256)
  const float* ow    = (const float*)d_in[13];  // (4, 128, 256)
  const float* lnw   = (const float*)d_in[14];
  const float* lnb   = (const float*)d_in[15];
  const float* hw    = (const float*)d_in[16];
  const float* hb    = (const float*)d_in[17];

  float* ws   = (float*)d_ws;
  float* zx   = ws;                                   // 10,535,840
  float* xbc  = zx + (size_t)BATCH*LH*DPROJ;          // 6,282,240
  float* ybuf = xbc + (size_t)BATCH*LH*CONVD;         // 4,194,304 (G aliases ybuf)
  float* G    = ybuf;
  float* Hin  = ybuf + 4194304;                       // 4,194,304
  float* dec  = Hin  + 4194304;                       // 1,024
  unsigned short* wH = (unsigned short*)(dec + 1024);      // 4*41*4*64*8 u16
  unsigned short* wL = wH + (size_t)DEPTH*NJT*4*64*8;      // same
  unsigned short* oH = wL + (size_t)DEPTH*NJT*4*64*8;      // 4*8*8*64*8 u16
  unsigned short* oL = oH + (size_t)DEPTH*8*8*64*8;        // same

  float* hout = (float*)d_out + 8;   // final h written directly into output

  k_cast_all<<<228, 256, 0, stream>>>(inw, ow, wH, wL, oH, oL);

  k_front_proj<<<BATCH*64, 512, 0, stream>>>(x, w1, b1, w2, b2, cls,
                                             wH, wL, dtb, zx);

  for (int i = 0; i < DEPTH; ++i) {
    int doProj = (i < DEPTH-1) ? 1 : 0;
    int nxt = doProj ? (i+1) : 0;
    k_chunk_state<<<BATCH*NH*NCH, 512, 0, stream>>>(
        zx, cw + (size_t)i*CONVD*4, cb + (size_t)i*CONVD, Alog + i*NH, G, dec, xbc);
    k_combine<<<BATCH*NH*4, 256, 0, stream>>>(G, dec, Hin);
    k_chunk_out<<<BATCH*NH*NCH, 512, 0, stream>>>(zx, xbc, Alog + i*NH, Hin, ybuf);
    k_out_fused<<<BATCH*64, 512, 0, stream>>>(
        ybuf, xbc, zx, Dh + i*NH, nw + (size_t)i*DIN,
        oH + (size_t)i*8*8*64*8, oL + (size_t)i*8*8*64*8,
        wH + (size_t)nxt*NJT*4*64*8, wL + (size_t)nxt*NJT*4*64*8,
        dtb + nxt*NH, hout, doProj);
  }

  k_head<<<BATCH, 128, 0, stream>>>(hout, lnw, lnb, hw, hb, (float*)d_out);
}

// Round 14
// 422.570 us; speedup vs baseline: 2.8286x; 1.0162x over previous
//
#include <hip/hip_runtime.h>
#include <math.h>

// Shapes (fixed by setup_inputs)
#define BATCH 8
#define TSEQ 2048
#define CIN 3
#define WIN 5
#define LSEQ 2044          // T - WIN + 1
#define LH 2045            // LSEQ + 1 (cls token appended)
#define DIM 128
#define DEPTH 4
#define DIN 256            // d_inner
#define NH 4               // heads
#define PDIM 64            // headdim
#define NSTATE 64          // d_state
#define CONVD 384          // d_inner + 2*d_state
#define DPROJ 644          // 2*d_inner + 2*d_state + nheads
#define NJT 41             // j-tiles of 16 (41*16 = 656 >= 644)
#define QC 64              // chunk length
#define NCH 32             // number of chunks
#define LDS2 68            // padded LDS row stride (shorts, 64-col frag buffers)
#define LDSY 268           // padded stride (shorts): 134 dwords ≡ 6 mod 32 -> frag reads bank-free
#define LDSH 140           // padded stride (shorts): 70 dwords ≡ 6 mod 32 -> bank-free, 8B-aligned rows
#define FTR 32             // tokens per k_front block
#define OTOK 32            // tokens per k_out_fused block (512-thread block, 8 waves)

typedef __attribute__((ext_vector_type(8))) short bf16x8;
typedef __attribute__((ext_vector_type(4))) float f32x4;
union Frag8 { bf16x8 v; uint2 u[2]; };

__device__ __forceinline__ float sigmoidf_(float x){ return 1.f/(1.f+__expf(-x)); }
__device__ __forceinline__ float siluf_(float x){ return x*sigmoidf_(x); }
__device__ __forceinline__ unsigned short f2bf(float f){   // RNE fp32->bf16
  unsigned int u = __float_as_uint(f);
  return (unsigned short)((u + 0x7FFFu + ((u >> 16) & 1u)) >> 16);
}
__device__ __forceinline__ float bf2f(unsigned short u){
  return __uint_as_float(((unsigned int)u) << 16);
}
__device__ __forceinline__ unsigned int pack2(float a, float b){  // [lo addr]=a
  return (unsigned int)f2bf(a) | ((unsigned int)f2bf(b) << 16);
}
__device__ __forceinline__ unsigned int pack2lo(float a, float b){
  float ra = a - bf2f(f2bf(a)), rb = b - bf2f(f2bf(b));
  return (unsigned int)f2bf(ra) | ((unsigned int)f2bf(rb) << 16);
}
__device__ __forceinline__ bf16x8 ldfrag(const unsigned short* base, int off){
  Frag8 f;
  f.u[0] = *(const uint2*)(base + off);
  f.u[1] = *(const uint2*)(base + off + 4);
  return f.v;
}

// ---------------------------------------------------------------- merged weight-cast
__global__ void __launch_bounds__(256) k_cast_all(
    const float* __restrict__ w, const float* __restrict__ ow,
    unsigned short* __restrict__ wH, unsigned short* __restrict__ wL,
    unsigned short* __restrict__ oH, unsigned short* __restrict__ oL) {
  int blk = blockIdx.x;
  if (blk < 164) {                            // inw: [ly][jt][kb][lane], 164*256 = 41984
    int gid = blk*256 + threadIdx.x;
    int lane = gid & 63;
    int kb = (gid >> 6) & 3;
    int jt = (gid >> 8) % NJT;
    int ly = gid / (NJT*4*64);
    int m = lane & 15, q = lane >> 4;
    int j = jt*16 + m;
    int k = kb*32 + q*8;
    unsigned short hi[8], lo[8];
    if (j < DPROJ) {
      const float* src = w + ((size_t)ly*DPROJ + j)*DIM + k;
#pragma unroll
      for (int i = 0; i < 8; ++i) {
        float v = src[i];
        hi[i] = f2bf(v);
        lo[i] = f2bf(v - bf2f(hi[i]));
      }
    } else {
#pragma unroll
      for (int i = 0; i < 8; ++i) { hi[i] = 0; lo[i] = 0; }
    }
    size_t dst = (size_t)gid*8;
    *(uint4*)(wH + dst) = *(const uint4*)hi;
    *(uint4*)(wL + dst) = *(const uint4*)lo;
  } else {                                    // ow: 64*256 = 16384
    int gid = (blk - 164)*256 + threadIdx.x;
    int lane = gid & 63;
    int kb = (gid >> 6) & 7;
    int jt = (gid >> 9) & 7;
    int ly = gid >> 12;
    int m = lane & 15, q = lane >> 4;
    int j = jt*16 + m;
    int k = kb*32 + q*8;
    const float* src = ow + ((size_t)ly*DIM + j)*DIN + k;
    unsigned short hi[8], lo[8];
#pragma unroll
    for (int i = 0; i < 8; ++i) {
      float v = src[i];
      hi[i] = f2bf(v);
      lo[i] = f2bf(v - bf2f(hi[i]));
    }
    size_t dst = (size_t)gid*8;
    *(uint4*)(oH + dst) = *(const uint4*)hi;
    *(uint4*)(oL + dst) = *(const uint4*)lo;
  }
}

// ---------------------------------------------------------------- front MLP + layer-0 in_proj
// R28 (R10-verified 494->474): in_proj fused; h tile in aliased bf16 LDS; cls inline.
__global__ void __launch_bounds__(512) k_front_proj(
    const float* __restrict__ x, const float* __restrict__ w1,
    const float* __restrict__ b1, const float* __restrict__ w2,
    const float* __restrict__ b2, const float* __restrict__ cls,
    const unsigned short* __restrict__ wH, const unsigned short* __restrict__ wL,
    const float* __restrict__ dtb, float* __restrict__ zx) {
  int t = threadIdx.x;
  int b = blockIdx.x >> 6;
  int c0 = (blockIdx.x & 63) * FTR;
  __shared__ __align__(16) float pool[108 + 2176 + 4096 + 8192];
  float* xs   = pool;
  float* w1s  = pool + 108;
  float* h1s  = pool + 108 + 2176;           // [32][128]
  float* part = pool + 108 + 2176 + 4096;    // [32][128][2]
  unsigned short* hsH = (unsigned short*)pool;
  unsigned short* hsL = hsH + 32*LDSH;       // aliases dead region by phase 3
  for (int i = t; i < (FTR+4)*CIN; i += 512) {
    int row = c0 + i/3, ch = i - (i/3)*3;
    xs[i] = (row < TSEQ) ? x[(size_t)b*TSEQ*CIN + (size_t)row*CIN + ch] : 0.f;
  }
  for (int i = t; i < DIM*15; i += 512) {
    int j = i/15, k = i - j*15;
    w1s[j*17+k] = w1[i];
  }
  __syncthreads();
  {
    int j = t & 127, rh = t >> 7;            // rh 0..3 -> 8 rows each
    float bias = b1[j];
    const float* wr = &w1s[j*17];
    for (int r = rh*8; r < rh*8+8; ++r) {
      float a = bias;
#pragma unroll
      for (int k = 0; k < 15; ++k) a += xs[r*3+k]*wr[k];
      h1s[r*128 + j] = 0.5f*a*(1.f + erff(a*0.70710678118654752f));  // exact gelu
    }
  }
  __syncthreads();
  {
    int j = t & 127, z = t >> 7;             // z 0..3
    int hf = z & 1, rh2 = z >> 1;            // k-half, row-half (16 rows)
    float4 wv[16];
    const float4* w2r = (const float4*)(w2 + (size_t)j*DIM + hf*64);
#pragma unroll
    for (int k4 = 0; k4 < 16; ++k4) wv[k4] = w2r[k4];
#pragma unroll 2
    for (int r = rh2*16; r < rh2*16+16; ++r) {
      const float4* hr = (const float4*)&h1s[r*128 + hf*64];
      float acc = 0.f;
#pragma unroll
      for (int k4 = 0; k4 < 16; ++k4) {
        float4 hv = hr[k4];
        acc += wv[k4].x*hv.x + wv[k4].y*hv.y + wv[k4].z*hv.z + wv[k4].w*hv.w;
      }
      part[(r*128 + j)*2 + hf] = acc;
    }
  }
  __syncthreads();
  {
    int c = t & 127, rh = t >> 7;            // 8 rows each
    float bias = b2[c];
    for (int r = rh*8; r < rh*8+8; ++r) {
      int l = c0 + r;
      float val;
      if (l < LSEQ)       val = part[(r*128 + c)*2] + part[(r*128 + c)*2 + 1] + bias;
      else if (l == LSEQ) val = cls[c];
      else                val = 0.f;
      unsigned short hi = f2bf(val);
      hsH[r*LDSH + c] = hi;
      hsL[r*LDSH + c] = f2bf(val - bf2f(hi));
    }
  }
  __syncthreads();
  int wave = t >> 6, lane = t & 63;
  int m = lane & 15, q = lane >> 4;
#pragma unroll 2
  for (int jt = wave; jt < NJT; jt += 8) {
    size_t woff = (((size_t)jt*4)*64 + lane)*8;
    bf16x8 bh[4], bl[4];
#pragma unroll
    for (int kb = 0; kb < 4; ++kb) {
      bh[kb] = *(const bf16x8*)(wH + woff + (size_t)kb*64*8);  // coalesced
      bl[kb] = *(const bf16x8*)(wL + woff + (size_t)kb*64*8);
    }
    f32x4 acc0 = {0.f, 0.f, 0.f, 0.f}, acc1 = {0.f, 0.f, 0.f, 0.f};
#pragma unroll
    for (int kb = 0; kb < 4; ++kb) {
      int o0 = m*LDSH + kb*32 + q*8;
      int o1 = (16 + m)*LDSH + kb*32 + q*8;  // 16*LDSH ≡ 0 mod 32 dwords
      bf16x8 a0h = ldfrag(hsH, o0), a0l = ldfrag(hsL, o0);
      bf16x8 a1h = ldfrag(hsH, o1), a1l = ldfrag(hsL, o1);
      acc0 = __builtin_amdgcn_mfma_f32_16x16x32_bf16(a0l, bh[kb], acc0, 0, 0, 0);
      acc0 = __builtin_amdgcn_mfma_f32_16x16x32_bf16(a0h, bl[kb], acc0, 0, 0, 0);
      acc0 = __builtin_amdgcn_mfma_f32_16x16x32_bf16(a0h, bh[kb], acc0, 0, 0, 0);
      acc1 = __builtin_amdgcn_mfma_f32_16x16x32_bf16(a1l, bh[kb], acc1, 0, 0, 0);
      acc1 = __builtin_amdgcn_mfma_f32_16x16x32_bf16(a1h, bl[kb], acc1, 0, 0, 0);
      acc1 = __builtin_amdgcn_mfma_f32_16x16x32_bf16(a1h, bh[kb], acc1, 0, 0, 0);
    }
    int jj = jt*16 + m;
    if (jj < DPROJ) {
      bool isdt = (jj >= 640);
      float bias = isdt ? dtb[jj - 640] : 0.f;
#pragma unroll
      for (int r = 0; r < 4; ++r) {
        int tok = c0 + q*4 + r;
        if (tok < LH) {
          float vv = acc0[r];
          if (isdt) { vv += bias; vv = (vv > 20.f) ? vv : log1pf(__expf(vv)); }
          zx[((size_t)b*LH + tok)*DPROJ + jj] = vv;
        }
        int tok1 = c0 + 16 + q*4 + r;
        if (tok1 < LH) {
          float vv = acc1[r];
          if (isdt) { vv += bias; vv = (vv > 20.f) ? vv : log1pf(__expf(vv)); }
          zx[((size_t)b*LH + tok1)*DPROJ + jj] = vv;
        }
      }
    }
  }
}

// ---------------------------------------------------------------- chunked SSD, phase A
// R31 (R13-verified 470->429): conv+silu fused in (streaming rolling-window);
// this kernel PRODUCES xbc. x-panel: every block (unique writer). B-panel:
// all compute, hd==0 stores. C-panel: hd==1 computes+stores.
__global__ void __launch_bounds__(512, 4) k_chunk_state(
    const float* __restrict__ zx, const float* __restrict__ cw,
    const float* __restrict__ cb, const float* __restrict__ A_log,
    float* __restrict__ G, float* __restrict__ dec, float* __restrict__ xbc) {
  int blk = blockIdx.x;
  int c = blk & (NCH-1), hd = (blk >> 5) & 3, b = blk >> 7;
  int t0 = c*QC;
  int tid = threadIdx.x;
  int wave = tid >> 6, lane = tid & 63;
  int wr = wave & 3, wh = wave >> 2;
  int m = lane & 15, q = lane >> 4;
  float A = -__expf(A_log[hd]);
  __shared__ __align__(16) unsigned short BcH[QC*LDS2], BcL[QC*LDS2]; // [n][s]
  __shared__ __align__(16) unsigned short XtH[QC*LDS2], XtL[QC*LDS2]; // [p][s]
  __shared__ float coef[QC];
  float dtv = 0.f;
  if (tid < 64) {
    int tg = t0 + tid;
    dtv = (tg < LH) ? zx[((size_t)b*LH + tg)*DPROJ + 640 + hd] : 0.f;
  }
  // ---- streaming conv: thread owns (panel, channel, 16-row quarter)
  int chIdx = tid & 127, half = tid >> 7;    // half 0..3 -> rows 16 each
  bool isB = (chIdx >= 64);
  int n = chIdx & 63;
  int xch = isB ? (DIN + n) : (hd*PDIM + n); // xbc channel
  int col = 256 + xch;                       // zx column
  const float4 wv4 = *(const float4*)(cw + xch*4);
  float bias = cb[xch];
  int s0 = half*16;
  float bb[16];                              // B-panel conv values (pre-coef)
  {
    float x3, x2, x1;
    int t3 = t0 + s0 - 3, t2_ = t0 + s0 - 2, t1_ = t0 + s0 - 1;
    x3 = (t3 >= 0 && t3 < LH) ? zx[((size_t)b*LH + t3)*DPROJ + col] : 0.f;
    x2 = (t2_ >= 0 && t2_ < LH) ? zx[((size_t)b*LH + t2_)*DPROJ + col] : 0.f;
    x1 = (t1_ >= 0 && t1_ < LH) ? zx[((size_t)b*LH + t1_)*DPROJ + col] : 0.f;
    float prev = 0.f;
#pragma unroll
    for (int i = 0; i < 16; ++i) {
      int s = s0 + i;
      int tg = t0 + s;
      float x0 = (tg < LH) ? zx[((size_t)b*LH + tg)*DPROJ + col] : 0.f;
      float a = bias;
      a += x3*wv4.x; a += x2*wv4.y; a += x1*wv4.z; a += x0*wv4.w;
      float out = (tg < LH) ? siluf_(a) : 0.f;
      if (tg < LH && (!isB || hd == 0))
        xbc[((size_t)b*LH + tg)*CONVD + xch] = out;
      if (isB) {
        bb[i] = out;                         // pack after coef is ready
      } else {
        if (i & 1) {                         // x-panel: straight to LDS in pairs
          int o = n*LDS2 + (s - 1);
          *(unsigned int*)(XtH + o) = pack2(prev, out);
          *(unsigned int*)(XtL + o) = pack2lo(prev, out);
        } else prev = out;
      }
      x3 = x2; x2 = x1; x1 = x0;
    }
  }
  // ---- C-panel (store-only) on hd==1 blocks: ch = tid&63, 8-row octant
  if (hd == 1) {
    int cc = tid & 63, oct = tid >> 6;       // oct 0..7
    int xch2 = DIN + NSTATE + cc;            // xbc channel 320+cc
    int col2 = 256 + xch2;                   // zx col 576+cc
    const float4 w2v = *(const float4*)(cw + xch2*4);
    float bias2 = cb[xch2];
    int s0c = oct*8;
    float x3, x2, x1;
    int t3 = t0 + s0c - 3, t2_ = t0 + s0c - 2, t1_ = t0 + s0c - 1;
    x3 = (t3 >= 0 && t3 < LH) ? zx[((size_t)b*LH + t3)*DPROJ + col2] : 0.f;
    x2 = (t2_ >= 0 && t2_ < LH) ? zx[((size_t)b*LH + t2_)*DPROJ + col2] : 0.f;
    x1 = (t1_ >= 0 && t1_ < LH) ? zx[((size_t)b*LH + t1_)*DPROJ + col2] : 0.f;
#pragma unroll
    for (int i = 0; i < 8; ++i) {
      int tg = t0 + s0c + i;
      float x0 = (tg < LH) ? zx[((size_t)b*LH + tg)*DPROJ + col2] : 0.f;
      float a = bias2;
      a += x3*w2v.x; a += x2*w2v.y; a += x1*w2v.z; a += x0*w2v.w;
      if (tg < LH) xbc[((size_t)b*LH + tg)*CONVD + xch2] = siluf_(a);
      x3 = x2; x2 = x1; x1 = x0;
    }
  }
  if (tid < 64) {
    float s = dtv;
#pragma unroll
    for (int off = 1; off < 64; off <<= 1) {
      float u = __shfl_up(s, off);
      if (tid >= off) s += u;
    }
    float cq = __shfl(s, 63);
    coef[tid] = __expf(A*(cq - s)) * dtv;
    if (tid == 63) dec[blk] = __expf(A * s);
  }
  __syncthreads();
  // B-panel: multiply by coef, pack to LDS
  if (isB) {
#pragma unroll
    for (int j = 0; j < 8; ++j) {
      int s = s0 + 2*j;
      float b0 = bb[2*j]   * coef[s];
      float b1 = bb[2*j+1] * coef[s+1];
      int o = n*LDS2 + s;
      *(unsigned int*)(BcH + o) = pack2(b0, b1);
      *(unsigned int*)(BcL + o) = pack2lo(b0, b1);
    }
  }
  __syncthreads();
  bf16x8 ah[2], al[2];
#pragma unroll
  for (int kc = 0; kc < 2; ++kc) {
    int off = (wr*16 + m)*LDS2 + kc*32 + q*8;
    ah[kc] = ldfrag(BcH, off);
    al[kc] = ldfrag(BcL, off);
  }
#pragma unroll
  for (int nth = 0; nth < 2; ++nth) {
    int nt = wh*2 + nth;
    f32x4 acc = {0.f,0.f,0.f,0.f};
#pragma unroll
    for (int kc = 0; kc < 2; ++kc) {
      int off = (nt*16 + m)*LDS2 + kc*32 + q*8;
      bf16x8 xh = ldfrag(XtH, off), xl = ldfrag(XtL, off);
      acc = __builtin_amdgcn_mfma_f32_16x16x32_bf16(al[kc], xh, acc, 0, 0, 0);
      acc = __builtin_amdgcn_mfma_f32_16x16x32_bf16(ah[kc], xl, acc, 0, 0, 0);
      acc = __builtin_amdgcn_mfma_f32_16x16x32_bf16(ah[kc], xh, acc, 0, 0, 0);
    }
    int p = nt*16 + m;
#pragma unroll
    for (int r = 0; r < 4; ++r) {
      int n2 = wr*16 + q*4 + r;
      G[(size_t)blk*4096 + n2*64 + p] = acc[r];
    }
  }
}

// ---------------------------------------------------------------- phase B: inter-chunk
// R24: 4-deep rotating load pipeline. (R11's last-block fusion regressed 2.5x —
// keep the 128-block kernel.)
__global__ void __launch_bounds__(256) k_combine(
    const float* __restrict__ G, const float* __restrict__ dec, float* __restrict__ Hin) {
  int bh = blockIdx.x >> 2, esp = blockIdx.x & 3;
  int e = esp*1024 + threadIdx.x*4;
  size_t base0 = (size_t)bh*NCH*4096 + e;
  float4 gq[4]; float dq[4];
#pragma unroll
  for (int k = 0; k < 4; ++k) {
    gq[k] = *(const float4*)(G + base0 + (size_t)k*4096);
    dq[k] = dec[bh*NCH + k];
  }
  float4 H = make_float4(0.f,0.f,0.f,0.f);
#pragma unroll 4
  for (int c = 0; c < NCH; ++c) {
    int slot = c & 3;
    float4 g = gq[slot]; float d = dq[slot];
    if (c + 4 < NCH) {
      gq[slot] = *(const float4*)(G + base0 + (size_t)(c+4)*4096);
      dq[slot] = dec[bh*NCH + c + 4];
    }
    *(float4*)(Hin + base0 + (size_t)c*4096) = H;   // carry-in for chunk c
    H.x = H.x*d + g.x; H.y = H.y*d + g.y; H.z = H.z*d + g.z; H.w = H.w*d + g.w;
  }
}

// ---------------------------------------------------------------- phase C: chunk output
// R30 (R12-verified): 512 threads (8 waves = wr x wh), same LDS, R24 prefetches.
__global__ void __launch_bounds__(512, 8) k_chunk_out(
    const float* __restrict__ zx, const float* __restrict__ xbc,
    const float* __restrict__ A_log, const float* __restrict__ Hin,
    float* __restrict__ y) {
  int blk = blockIdx.x;
  int c = blk & (NCH-1), hd = (blk >> 5) & 3, b = blk >> 7;
  int t0 = c*QC;
  int tid = threadIdx.x;
  int wave = tid >> 6, lane = tid & 63;
  int wr = wave & 3, wh = wave >> 2;
  int m = lane & 15, q = lane >> 4;
  float A = -__expf(A_log[hd]);
  __shared__ __align__(16) unsigned short P0H[QC*LDS2], P0L[QC*LDS2]; // C, then mask
  __shared__ __align__(16) unsigned short P1H[QC*LDS2], P1L[QC*LDS2]; // B, HinT, Xt
  __shared__ float cum[QC], dts[QC], pref[QC];
  float dtv = 0.f;
  if (tid < 64) {
    int tg = t0 + tid;
    dtv = (tg < LH) ? zx[((size_t)b*LH + tg)*DPROJ + 640 + hd] : 0.f;
  }
  float pbv[8], pcv[8];
#pragma unroll
  for (int it = 0; it < 4; ++it) {
    int i = tid + it*512;
    int s = i >> 5, j2 = (i & 31)*2;
    int tg = t0 + s;
    float b0 = 0.f, b1 = 0.f, c0_ = 0.f, c1_ = 0.f;
    if (tg < LH) {
      size_t row = ((size_t)b*LH + tg)*CONVD;
      float2 bv = *(const float2*)(xbc + row + DIN + j2);
      float2 cv = *(const float2*)(xbc + row + DIN + NSTATE + j2);
      b0 = bv.x; b1 = bv.y; c0_ = cv.x; c1_ = cv.y;
    }
    pbv[it*2] = b0; pbv[it*2+1] = b1; pcv[it*2] = c0_; pcv[it*2+1] = c1_;
  }
  size_t hbase = (size_t)blk*4096;
  float hv[8];
#pragma unroll
  for (int it = 0; it < 4; ++it) {
    int i = tid + it*512;
    int p = i & 63, n2 = (i >> 6)*2;
    hv[it*2]   = Hin[hbase + (size_t)n2*64 + p];
    hv[it*2+1] = Hin[hbase + (size_t)(n2+1)*64 + p];
  }
  if (tid < 64) {
    float s = dtv;
#pragma unroll
    for (int off = 1; off < 64; off <<= 1) {
      float u = __shfl_up(s, off);
      if (tid >= off) s += u;
    }
    dts[tid] = dtv; cum[tid] = s; pref[tid] = __expf(A*s);
  }
#pragma unroll
  for (int it = 0; it < 4; ++it) {
    int i = tid + it*512;
    int s = i >> 5, j2 = (i & 31)*2;
    int o = s*LDS2 + j2;
    *(unsigned int*)(P1H + o) = pack2(pbv[it*2], pbv[it*2+1]);
    *(unsigned int*)(P1L + o) = pack2lo(pbv[it*2], pbv[it*2+1]);
    *(unsigned int*)(P0H + o) = pack2(pcv[it*2], pcv[it*2+1]);
    *(unsigned int*)(P0L + o) = pack2lo(pcv[it*2], pcv[it*2+1]);
  }
  __syncthreads();                                    // A
  bf16x8 ch[2], cl[2];
#pragma unroll
  for (int kc = 0; kc < 2; ++kc) {
    int off = (wr*16 + m)*LDS2 + kc*32 + q*8;
    ch[kc] = ldfrag(P0H, off);
    cl[kc] = ldfrag(P0L, off);
  }
  f32x4 sacc[2];
#pragma unroll
  for (int nth = 0; nth < 2; ++nth) {
    int nt = wh*2 + nth;
    f32x4 a1 = {0.f,0.f,0.f,0.f};
#pragma unroll
    for (int kc = 0; kc < 2; ++kc) {
      int off = (nt*16 + m)*LDS2 + kc*32 + q*8;
      bf16x8 bh = ldfrag(P1H, off), bl = ldfrag(P1L, off);
      a1 = __builtin_amdgcn_mfma_f32_16x16x32_bf16(cl[kc], bh, a1, 0, 0, 0);
      a1 = __builtin_amdgcn_mfma_f32_16x16x32_bf16(ch[kc], bl, a1, 0, 0, 0);
      a1 = __builtin_amdgcn_mfma_f32_16x16x32_bf16(ch[kc], bh, a1, 0, 0, 0);
    }
    sacc[nth] = a1;
  }
  __syncthreads();                                    // B: C,B dead
  float xv[8];
#pragma unroll
  for (int it = 0; it < 4; ++it) {
    int i = tid + it*512;
    int p = i & 63, s2 = (i >> 6)*2;
    int tg = t0 + s2;
    xv[it*2]   = (tg < LH)   ? xbc[((size_t)b*LH + tg)*CONVD + hd*PDIM + p]   : 0.f;
    xv[it*2+1] = (tg+1 < LH) ? xbc[((size_t)b*LH + tg+1)*CONVD + hd*PDIM + p] : 0.f;
  }
#pragma unroll
  for (int nth = 0; nth < 2; ++nth) {
    int nt = wh*2 + nth;
    int s = nt*16 + m;
#pragma unroll
    for (int r = 0; r < 4; ++r) {
      int t = wr*16 + q*4 + r;
      float mv = 0.f;
      if (s <= t) mv = sacc[nth][r] * __expf(A*(cum[t] - cum[s])) * dts[s];
      unsigned short hi = f2bf(mv);
      P0H[t*LDS2 + s] = hi;
      P0L[t*LDS2 + s] = f2bf(mv - bf2f(hi));
    }
  }
#pragma unroll
  for (int it = 0; it < 4; ++it) {
    int i = tid + it*512;
    int p = i & 63, n2 = (i >> 6)*2;
    int o = p*LDS2 + n2;
    *(unsigned int*)(P1H + o) = pack2(hv[it*2], hv[it*2+1]);
    *(unsigned int*)(P1L + o) = pack2lo(hv[it*2], hv[it*2+1]);
  }
  __syncthreads();                                    // C
  f32x4 y2a[2];
#pragma unroll
  for (int nth = 0; nth < 2; ++nth) {
    int nt = wh*2 + nth;
    f32x4 a2 = {0.f,0.f,0.f,0.f};
#pragma unroll
    for (int kc = 0; kc < 2; ++kc) {
      int off = (nt*16 + m)*LDS2 + kc*32 + q*8;
      bf16x8 th = ldfrag(P1H, off), tl = ldfrag(P1L, off);
      a2 = __builtin_amdgcn_mfma_f32_16x16x32_bf16(cl[kc], th, a2, 0, 0, 0);
      a2 = __builtin_amdgcn_mfma_f32_16x16x32_bf16(ch[kc], tl, a2, 0, 0, 0);
      a2 = __builtin_amdgcn_mfma_f32_16x16x32_bf16(ch[kc], th, a2, 0, 0, 0);
    }
    y2a[nth] = a2;
  }
  bf16x8 mh[2], ml[2];
#pragma unroll
  for (int kc = 0; kc < 2; ++kc) {
    int off = (wr*16 + m)*LDS2 + kc*32 + q*8;
    mh[kc] = ldfrag(P0H, off);
    ml[kc] = ldfrag(P0L, off);
  }
  __syncthreads();                                    // D: Hin dead
#pragma unroll
  for (int it = 0; it < 4; ++it) {
    int i = tid + it*512;
    int p = i & 63, s2 = (i >> 6)*2;
    int o = p*LDS2 + s2;
    *(unsigned int*)(P1H + o) = pack2(xv[it*2], xv[it*2+1]);
    *(unsigned int*)(P1L + o) = pack2lo(xv[it*2], xv[it*2+1]);
  }
  __syncthreads();                                    // E
#pragma unroll
  for (int nth = 0; nth < 2; ++nth) {
    int nt = wh*2 + nth;
    f32x4 a1 = {0.f,0.f,0.f,0.f};
#pragma unroll
    for (int kc = 0; kc < 2; ++kc) {
      int off = (nt*16 + m)*LDS2 + kc*32 + q*8;
      bf16x8 th = ldfrag(P1H, off), tl = ldfrag(P1L, off);
      a1 = __builtin_amdgcn_mfma_f32_16x16x32_bf16(ml[kc], th, a1, 0, 0, 0);
      a1 = __builtin_amdgcn_mfma_f32_16x16x32_bf16(mh[kc], tl, a1, 0, 0, 0);
      a1 = __builtin_amdgcn_mfma_f32_16x16x32_bf16(mh[kc], th, a1, 0, 0, 0);
    }
    int p = nt*16 + m;
#pragma unroll
    for (int r = 0; r < 4; ++r) {
      int t = wr*16 + q*4 + r, tg = t0 + t;
      if (tg < LH)
        y[((size_t)b*LH + tg)*DIN + hd*PDIM + p] = a1[r] + pref[t]*y2a[nth][r];
    }
  }
}

// ---------------------------------------------------------------- gate+rmsnorm+out_proj
// FUSED with next layer's in_proj. R22 512-thread OTOK=32; R23 weight prefetch.
// R32: final LN + head FUSED into the last-layer block covering the cls row
// (LSEQ=2044 lives in block (b, l0=2016)). Row values stashed as f32 in hfv[],
// then k_head's exact 128-thread reduction (same lane/wave structure, same
// barrier placement, same red[] reuse) runs as a block-uniform epilogue.
// k_head dispatch deleted.
__global__ void __launch_bounds__(512, 2) k_out_fused(
    const float* __restrict__ y, const float* __restrict__ xbc,
    float* __restrict__ zx, const float* __restrict__ Dh,
    const float* __restrict__ nw, const unsigned short* __restrict__ oH,
    const unsigned short* __restrict__ oL,
    const unsigned short* __restrict__ wH, const unsigned short* __restrict__ wL,
    const float* __restrict__ dtb, float* __restrict__ hout, int doProj,
    const float* __restrict__ lnw, const float* __restrict__ lnb,
    const float* __restrict__ hw, const float* __restrict__ hb,
    float* __restrict__ out) {
  int b = blockIdx.x >> 6;
  int l0 = (blockIdx.x & 63) * OTOK;
  int t = threadIdx.x;
  __shared__ __align__(16) unsigned short yH[OTOK*LDSY], yL[OTOK*LDSY];
  __shared__ __align__(16) unsigned short hsH[OTOK*LDSH], hsL[OTOK*LDSH];
  __shared__ float red[OTOK][4];
  __shared__ float rs[OTOK];
  __shared__ float hfv[DIM];
  __shared__ float redh[2];
  bool doHead = (!doProj) && ((blockIdx.x & 63) == 63);
  int wave = t >> 6, lane = t & 63;
  bf16x8 pwh[4], pwl[4];
#pragma unroll
  for (int kb = 0; kb < 4; ++kb) {
    size_t woff = (((size_t)wave*8 + kb)*64 + lane)*8;
    pwh[kb] = *(const bf16x8*)(oH + woff);
    pwl[kb] = *(const bf16x8*)(oL + woff);
  }
  int c = t & 255;
  int rh = t >> 8;           // row-half: 0 -> rows 0..15, 1 -> rows 16..31
  int r0 = rh*16;
  int hd = c >> 6;
  float dcoef = Dh[hd];
  float nwc = nw[c];
  float v[16];
#pragma unroll
  for (int r = 0; r < 16; ++r) {
    int l = l0 + r0 + r;
    float val = 0.f;
    if (l < LH) {
      size_t row = (size_t)b*LH + l;
      float ys = y[row*DIN + c];
      float xh = xbc[row*CONVD + c];
      float z  = zx[row*DPROJ + c];
      val = (ys + dcoef*xh) * siluf_(z);
    }
    v[r] = val;
  }
  int qw = wave & 3;         // channel-quarter within the row-half
#pragma unroll
  for (int r = 0; r < 16; ++r) {
    float sq = v[r]*v[r];
    for (int off = 32; off > 0; off >>= 1) sq += __shfl_down(sq, off);
    if (lane == 0) red[r0 + r][qw] = sq;
  }
  __syncthreads();
  if (t < OTOK) {
    float sm = red[t][0]+red[t][1]+red[t][2]+red[t][3];
    rs[t] = rsqrtf(sm/(float)DIN + 1e-5f);
  }
  __syncthreads();
#pragma unroll
  for (int r = 0; r < 16; ++r) {
    float val = v[r] * rs[r0 + r] * nwc;
    unsigned short hi = f2bf(val);
    yH[(r0 + r)*LDSY + c] = hi;
    yL[(r0 + r)*LDSY + c] = f2bf(val - bf2f(hi));
  }
  __syncthreads();
  int m = lane & 15, q = lane >> 4;
  {
    int jt = wave;                          // 8 waves <-> 8 j-tiles
    f32x4 acc0 = {0.f,0.f,0.f,0.f}, acc1 = {0.f,0.f,0.f,0.f};
#pragma unroll
    for (int kb = 0; kb < 8; ++kb) {
      bf16x8 bh, bl;
      if (kb < 4) { bh = pwh[kb]; bl = pwl[kb]; }
      else {
        size_t woff = (((size_t)jt*8 + kb)*64 + lane)*8;   // coalesced
        bh = *(const bf16x8*)(oH + woff);
        bl = *(const bf16x8*)(oL + woff);
      }
      int o0 = m*LDSY + kb*32 + q*8;
      int o1 = (16 + m)*LDSY + kb*32 + q*8;  // 16*LDSY ≡ 0 mod 32 dwords: same bank pattern
      bf16x8 a0h = ldfrag(yH, o0), a0l = ldfrag(yL, o0);
      bf16x8 a1h = ldfrag(yH, o1), a1l = ldfrag(yL, o1);
      acc0 = __builtin_amdgcn_mfma_f32_16x16x32_bf16(a0l, bh, acc0, 0, 0, 0);
      acc0 = __builtin_amdgcn_mfma_f32_16x16x32_bf16(a0h, bl, acc0, 0, 0, 0);
      acc0 = __builtin_amdgcn_mfma_f32_16x16x32_bf16(a0h, bh, acc0, 0, 0, 0);
      acc1 = __builtin_amdgcn_mfma_f32_16x16x32_bf16(a1l, bh, acc1, 0, 0, 0);
      acc1 = __builtin_amdgcn_mfma_f32_16x16x32_bf16(a1h, bl, acc1, 0, 0, 0);
      acc1 = __builtin_amdgcn_mfma_f32_16x16x32_bf16(a1h, bh, acc1, 0, 0, 0);
    }
    int j = jt*16 + m;                      // D col = lane&15
#pragma unroll
    for (int r = 0; r < 4; ++r) {
      int rr = q*4 + r;                     // frag 0 rows
      float val = acc0[r];
      unsigned short hi = f2bf(val);
      hsH[rr*LDSH + j] = hi;
      hsL[rr*LDSH + j] = f2bf(val - bf2f(hi));
      int l = l0 + rr;
      if (!doProj && l < LH) hout[((size_t)b*LH + l)*DIM + j] = val;
      if (doHead && l == LSEQ) hfv[j] = val;
      int rr1 = 16 + q*4 + r;               // frag 1 rows
      float val1 = acc1[r];
      unsigned short hi1 = f2bf(val1);
      hsH[rr1*LDSH + j] = hi1;
      hsL[rr1*LDSH + j] = f2bf(val1 - bf2f(hi1));
      int l1 = l0 + rr1;
      if (!doProj && l1 < LH) hout[((size_t)b*LH + l1)*DIM + j] = val1;
      if (doHead && l1 == LSEQ) hfv[j] = val1;
    }
  }
  if (doHead) {
    // ---- k_head epilogue, bit-identical FP order (128 active threads, 2 waves)
    __syncthreads();
    float vh = (t < DIM) ? hfv[t] : 0.f;
    int wv2 = t >> 6;
    float s = vh;
    for (int off = 32; off > 0; off >>= 1) s += __shfl_down(s, off);
    if (t < DIM && lane == 0) redh[wv2] = s;
    __syncthreads();
    float mean = (redh[0]+redh[1]) / (float)DIM;
    __syncthreads();
    float d = vh - mean; float sq = d*d;
    for (int off = 32; off > 0; off >>= 1) sq += __shfl_down(sq, off);
    if (t < DIM && lane == 0) redh[wv2] = sq;
    __syncthreads();
    float var = (redh[0]+redh[1]) / (float)DIM;
    float cn = 0.f, dot = 0.f;
    if (t < DIM) {
      cn = d*rsqrtf(var + 1e-5f)*lnw[t] + lnb[t];
      dot = cn*hw[t];
    }
    __syncthreads();
    for (int off = 32; off > 0; off >>= 1) dot += __shfl_down(dot, off);
    if (t < DIM && lane == 0) redh[wv2] = dot;
    __syncthreads();
    if (t == 0) out[b] = redh[0]+redh[1] + hb[0];
  }
  if (!doProj) return;
  __syncthreads();
  // ---- in_proj of next layer from the LDS h tile (32 rows, 8 waves)
#pragma unroll 2
  for (int jt = wave; jt < NJT; jt += 8) {
    size_t woff = (((size_t)jt*4)*64 + lane)*8;
    bf16x8 bh[4], bl[4];
#pragma unroll
    for (int kb = 0; kb < 4; ++kb) {
      bh[kb] = *(const bf16x8*)(wH + woff + (size_t)kb*64*8);  // coalesced
      bl[kb] = *(const bf16x8*)(wL + woff + (size_t)kb*64*8);
    }
    f32x4 acc0 = {0.f, 0.f, 0.f, 0.f}, acc1 = {0.f, 0.f, 0.f, 0.f};
#pragma unroll
    for (int kb = 0; kb < 4; ++kb) {
      int o0 = m*LDSH + kb*32 + q*8;
      int o1 = (16 + m)*LDSH + kb*32 + q*8;  // 16*LDSH ≡ 0 mod 32 dwords
      bf16x8 a0h = ldfrag(hsH, o0), a0l = ldfrag(hsL, o0);
      bf16x8 a1h = ldfrag(hsH, o1), a1l = ldfrag(hsL, o1);
      acc0 = __builtin_amdgcn_mfma_f32_16x16x32_bf16(a0l, bh[kb], acc0, 0, 0, 0);
      acc0 = __builtin_amdgcn_mfma_f32_16x16x32_bf16(a0h, bl[kb], acc0, 0, 0, 0);
      acc0 = __builtin_amdgcn_mfma_f32_16x16x32_bf16(a0h, bh[kb], acc0, 0, 0, 0);
      acc1 = __builtin_amdgcn_mfma_f32_16x16x32_bf16(a1l, bh[kb], acc1, 0, 0, 0);
      acc1 = __builtin_amdgcn_mfma_f32_16x16x32_bf16(a1h, bl[kb], acc1, 0, 0, 0);
      acc1 = __builtin_amdgcn_mfma_f32_16x16x32_bf16(a1h, bh[kb], acc1, 0, 0, 0);
    }
    int jj = jt*16 + m;
    if (jj < DPROJ) {
      bool isdt = (jj >= 640);
      float bias = isdt ? dtb[jj - 640] : 0.f;
#pragma unroll
      for (int r = 0; r < 4; ++r) {
        int tok = l0 + q*4 + r;
        if (tok < LH) {
          float vv = acc0[r];
          if (isdt) { vv += bias; vv = (vv > 20.f) ? vv : log1pf(__expf(vv)); }
          zx[((size_t)b*LH + tok)*DPROJ + jj] = vv;
        }
        int tok1 = l0 + 16 + q*4 + r;
        if (tok1 < LH) {
          float vv = acc1[r];
          if (isdt) { vv += bias; vv = (vv > 20.f) ? vv : log1pf(__expf(vv)); }
          zx[((size_t)b*LH + tok1)*DPROJ + jj] = vv;
        }
      }
    }
  }
}

extern "C" void kernel_launch(void* const* d_in, const int* in_sizes, int n_in,
                              void* d_out, int out_size, void* d_ws, size_t ws_size,
                              hipStream_t stream) {
  const float* x     = (const float*)d_in[0];
  const float* w1    = (const float*)d_in[1];
  const float* b1    = (const float*)d_in[2];
  const float* w2    = (const float*)d_in[3];
  const float* b2    = (const float*)d_in[4];
  const float* cls   = (const float*)d_in[5];
  const float* inw   = (const float*)d_in[6];   // (4, 644, 128)
  const float* cw    = (const float*)d_in[7];   // (4, 384, 4)
  const float* cb    = (const float*)d_in[8];   // (4, 384)
  const float* dtb   = (const float*)d_in[9];   // (4, 4)
  const float* Alog  = (const float*)d_in[10];  // (4, 4)
  const float* Dh    = (const float*)d_in[11];  // (4, 4)
  const float* nw    = (const float*)d_in[12];  // (4, 256)
  const float* ow    = (const float*)d_in[13];  // (4, 128, 256)
  const float* lnw   = (const float*)d_in[14];
  const float* lnb   = (const float*)d_in[15];
  const float* hw    = (const float*)d_in[16];
  const float* hb    = (const float*)d_in[17];

  float* ws   = (float*)d_ws;
  float* zx   = ws;                                   // 10,535,840
  float* xbc  = zx + (size_t)BATCH*LH*DPROJ;          // 6,282,240
  float* ybuf = xbc + (size_t)BATCH*LH*CONVD;         // 4,194,304 (G aliases ybuf)
  float* G    = ybuf;
  float* Hin  = ybuf + 4194304;                       // 4,194,304
  float* dec  = Hin  + 4194304;                       // 1,024
  unsigned short* wH = (unsigned short*)(dec + 1024);      // 4*41*4*64*8 u16
  unsigned short* wL = wH + (size_t)DEPTH*NJT*4*64*8;      // same
  unsigned short* oH = wL + (size_t)DEPTH*NJT*4*64*8;      // 4*8*8*64*8 u16
  unsigned short* oL = oH + (size_t)DEPTH*8*8*64*8;        // same

  float* hout = (float*)d_out + 8;   // final h written directly into output

  k_cast_all<<<228, 256, 0, stream>>>(inw, ow, wH, wL, oH, oL);

  k_front_proj<<<BATCH*64, 512, 0, stream>>>(x, w1, b1, w2, b2, cls,
                                             wH, wL, dtb, zx);

  for (int i = 0; i < DEPTH; ++i) {
    int doProj = (i < DEPTH-1) ? 1 : 0;
    int nxt = doProj ? (i+1) : 0;
    k_chunk_state<<<BATCH*NH*NCH, 512, 0, stream>>>(
        zx, cw + (size_t)i*CONVD*4, cb + (size_t)i*CONVD, Alog + i*NH, G, dec, xbc);
    k_combine<<<BATCH*NH*4, 256, 0, stream>>>(G, dec, Hin);
    k_chunk_out<<<BATCH*NH*NCH, 512, 0, stream>>>(zx, xbc, Alog + i*NH, Hin, ybuf);
    k_out_fused<<<BATCH*64, 512, 0, stream>>>(
        ybuf, xbc, zx, Dh + i*NH, nw + (size_t)i*DIN,
        oH + (size_t)i*8*8*64*8, oL + (size_t)i*8*8*64*8,
        wH + (size_t)nxt*NJT*4*64*8, wL + (size_t)nxt*NJT*4*64*8,
        dtb + nxt*NH, hout, doProj,
        lnw, lnb, hw, hb, (float*)d_out);
  }
}